// Round 1
// baseline (11875.671 us; speedup 1.0000x reference)
//
#include <hip/hip_runtime.h>
#include <math.h>

#define N_NODES 30000
#define N_EDGES 480000
#define HDIM 128
#define IN1 258   // 2H+2

__device__ __forceinline__ float silu_f(float v) {
  return v / (1.0f + __expf(-v));
}

// ---------------- output init: out = [h | x] ----------------
__global__ void init_out_kernel(const float* __restrict__ h,
                                const float* __restrict__ x,
                                float* __restrict__ out) {
  int idx = blockIdx.x * 256 + threadIdx.x;   // grid exactly covers N*128
  out[idx] = h[idx];
  if (idx < N_NODES * 3) out[N_NODES * HDIM + idx] = x[idx];
}

// ---------------- CNOT ring permutation g[c] ----------------
__global__ void perm_kernel(int* __restrict__ g) {
  int i = threadIdx.x;
  int v = i;
  // g[i] = f_(0,1)(f_(1,2)(...f_(6,0)(i))); apply innermost (6,0) first
  const int cs[7] = {6, 5, 4, 3, 2, 1, 0};
  const int ts[7] = {0, 6, 5, 4, 3, 2, 1};
#pragma unroll
  for (int p = 0; p < 7; ++p) {
    int cb = (v >> (6 - cs[p])) & 1;
    v = v ^ (cb << (6 - ts[p]));
  }
  g[i] = v;
}

// ---------------- build augmented [A_h + iI | I] ----------------
// A_h = (Are + i Aim) + (Are + i Aim)^H
__global__ void build_aug_kernel(const float* __restrict__ Are,
                                 const float* __restrict__ Aim,
                                 float2* __restrict__ aug) {
  int lj = blockIdx.y;
  int r = blockIdx.x;
  int c = threadIdx.x;   // 0..255
  const float* are = Are + (size_t)lj * 16384;
  const float* aim = Aim + (size_t)lj * 16384;
  float2 v;
  if (c < 128) {
    float re = are[r * 128 + c] + are[c * 128 + r];
    float im = aim[r * 128 + c] - aim[c * 128 + r];
    if (c == r) im += 1.0f;
    v = make_float2(re, im);
  } else {
    v = make_float2((c - 128) == r ? 1.0f : 0.0f, 0.0f);
  }
  aug[(size_t)lj * 128 * 256 + r * 256 + c] = v;
}

// ---------------- in-place Gauss-Jordan (no pivoting; matrix is
// Hermitian+iI so every leading principal minor is well conditioned) ----
__global__ __launch_bounds__(1024) void gj_kernel(float2* __restrict__ augg) {
  float2* M = augg + (size_t)blockIdx.x * 128 * 256;
  __shared__ float2 rowbuf[256];
  __shared__ float2 fbuf[128];
  __shared__ float2 ipiv_s;
  const int tid = threadIdx.x;
  for (int p = 0; p < 128; ++p) {
    if (tid == 0) {
      float2 piv = M[p * 256 + p];
      float d = piv.x * piv.x + piv.y * piv.y;
      ipiv_s = make_float2(piv.x / d, -piv.y / d);
    }
    __syncthreads();
    float2 ip = ipiv_s;
    if (tid < 256) {
      float2 m = M[p * 256 + tid];
      float2 s = make_float2(m.x * ip.x - m.y * ip.y, m.x * ip.y + m.y * ip.x);
      rowbuf[tid] = s;
      M[p * 256 + tid] = s;
    } else if (tid < 384) {
      int r = tid - 256;
      fbuf[r] = (r == p) ? make_float2(0.f, 0.f) : M[r * 256 + p];
    }
    __syncthreads();
    const int c = tid & 255, rg = tid >> 8;   // rg 0..3
    float2 pr = rowbuf[c];
#pragma unroll 4
    for (int rr = 0; rr < 32; ++rr) {
      int r = rg * 32 + rr;
      if (r != p) {
        float2 f = fbuf[r];
        float2 m = M[r * 256 + c];
        m.x -= f.x * pr.x - f.y * pr.y;
        m.y -= f.x * pr.y + f.y * pr.x;
        M[r * 256 + c] = m;
      }
    }
    __syncthreads();
  }
}

// ---------------- q = (A_h - iI) * Binv ----------------
__global__ void qmat_kernel(const float* __restrict__ Are,
                            const float* __restrict__ Aim,
                            const float2* __restrict__ augg,
                            float2* __restrict__ qm) {
  int lj = blockIdx.y;
  int idx = blockIdx.x * 256 + threadIdx.x;
  int r = idx >> 7, c = idx & 127;
  const float* are = Are + (size_t)lj * 16384;
  const float* aim = Aim + (size_t)lj * 16384;
  const float2* binv = augg + (size_t)lj * 128 * 256;
  float2 acc = make_float2(0.f, 0.f);
  for (int k = 0; k < 128; ++k) {
    float re = are[r * 128 + k] + are[k * 128 + r];
    float im = aim[r * 128 + k] - aim[k * 128 + r];
    if (k == r) im -= 1.0f;
    float2 b = binv[k * 256 + 128 + c];
    acc.x += re * b.x - im * b.y;
    acc.y += re * b.y + im * b.x;
  }
  qm[(size_t)lj * 16384 + idx] = acc;
}

// ---------------- Gk = (RY*RX)^(kron 7), elementwise ----------------
__global__ void gk_kernel(const float* __restrict__ coeffs,
                          float2* __restrict__ gkm) {
  int lj = blockIdx.y;
  float a = coeffs[lj * 2 + 0], b = coeffs[lj * 2 + 1];
  float ca = cosf(0.5f * a), sa = sinf(0.5f * a);
  float cb = cosf(0.5f * b), sb = sinf(0.5f * b);
  // G = RY @ RX
  float2 G[2][2];
  G[0][0] = make_float2(cb * ca, sb * sa);
  G[0][1] = make_float2(-sb * ca, -cb * sa);
  G[1][0] = make_float2(sb * ca, -cb * sa);
  G[1][1] = make_float2(cb * ca, -sb * sa);
  int idx = blockIdx.x * 256 + threadIdx.x;
  int r = idx >> 7, c = idx & 127;
  float2 acc = make_float2(1.f, 0.f);
#pragma unroll
  for (int bit = 6; bit >= 0; --bit) {
    float2 g = G[(r >> bit) & 1][(c >> bit) & 1];
    acc = make_float2(acc.x * g.x - acc.y * g.y, acc.x * g.y + acc.y * g.x);
  }
  gkm[(size_t)lj * 16384 + idx] = acc;
}

// ---------------- N_j[i][c] = sum_k q[k][i] * Gk[g[c]][k] ----------------
__global__ void nj_kernel(const float2* __restrict__ qm,
                          const float2* __restrict__ gkm,
                          const int* __restrict__ g,
                          float2* __restrict__ njm) {
  int lj = blockIdx.y;
  int idx = blockIdx.x * 256 + threadIdx.x;
  int i = idx >> 7, c = idx & 127;
  int gc = g[c];
  const float2* q = qm + (size_t)lj * 16384;
  const float2* gk = gkm + (size_t)lj * 16384;
  float2 acc = make_float2(0.f, 0.f);
  for (int k = 0; k < 128; ++k) {
    float2 qa = q[k * 128 + i];
    float2 gb = gk[gc * 128 + k];
    acc.x += qa.x * gb.x - qa.y * gb.y;
    acc.y += qa.x * gb.y + qa.y * gb.x;
  }
  njm[(size_t)lj * 16384 + idx] = acc;
}

// ---------------- U_l = N_{l,0} @ N_{l,1} ----------------
__global__ void compose_kernel(const float2* __restrict__ njm,
                               float2* __restrict__ um) {
  int l = blockIdx.y;
  int idx = blockIdx.x * 256 + threadIdx.x;
  int i = idx >> 7, c = idx & 127;
  const float2* n0 = njm + (size_t)(l * 2 + 0) * 16384;
  const float2* n1 = njm + (size_t)(l * 2 + 1) * 16384;
  float2 acc = make_float2(0.f, 0.f);
  for (int k = 0; k < 128; ++k) {
    float2 a = n0[i * 128 + k];
    float2 b = n1[k * 128 + c];
    acc.x += a.x * b.x - a.y * b.y;
    acc.y += a.x * b.y + a.y * b.x;
  }
  um[(size_t)l * 16384 + idx] = acc;
}

// ---------------- Wqd_l = Re(U_l) @ dec_w_l ----------------
__global__ void wqd_kernel(const float2* __restrict__ um,
                           const float* __restrict__ decw,
                           float* __restrict__ wqd) {
  int l = blockIdx.y;
  int idx = blockIdx.x * 256 + threadIdx.x;
  int i = idx >> 7, c = idx & 127;
  const float2* u = um + (size_t)l * 16384;
  const float* dw = decw + (size_t)l * 16384;
  float acc = 0.f;
  for (int k = 0; k < 128; ++k) acc += u[i * 128 + k].x * dw[k * 128 + c];
  wqd[(size_t)l * 16384 + idx] = acc;
}

// ---------------- edge MLP + scatter-add into agg ----------------
// 32 edges/block, 256 threads: thread (e = tid&31, cg = tid>>5) computes
// 16 output cols for its edge.
__global__ __launch_bounds__(256) void edge_mlp_kernel(
    const float* __restrict__ h, const int* __restrict__ ei,
    const float* __restrict__ x, const float* __restrict__ ea,
    const float* __restrict__ W1, const float* __restrict__ b1,
    const float* __restrict__ W2, const float* __restrict__ b2,
    float* __restrict__ agg) {
  __shared__ float in_tile[32 * IN1];   // stride 258: 2-way LDS alias, free
  __shared__ float m1[32 * 129];        // stride 129: conflict-free
  __shared__ int rowidx[32];
  const int tid = threadIdx.x;
  const int e0 = blockIdx.x * 32;
  {
    const int e = tid >> 3, j = tid & 7;
    const int edge = e0 + e;
    const int r = ei[edge], c = ei[N_EDGES + edge];
    if (j == 0) rowidx[e] = r;
    const float4* hr = (const float4*)(h + (size_t)r * HDIM);
    const float4* hc = (const float4*)(h + (size_t)c * HDIM);
    float* dst = &in_tile[e * IN1];
#pragma unroll
    for (int t = 0; t < 4; ++t) {
      const int c4 = j + t * 8;
      float4 v = hr[c4];
      dst[c4 * 4 + 0] = v.x; dst[c4 * 4 + 1] = v.y;
      dst[c4 * 4 + 2] = v.z; dst[c4 * 4 + 3] = v.w;
      float4 w = hc[c4];
      dst[128 + c4 * 4 + 0] = w.x; dst[128 + c4 * 4 + 1] = w.y;
      dst[128 + c4 * 4 + 2] = w.z; dst[128 + c4 * 4 + 3] = w.w;
    }
    if (j == 1) {
      float dx = x[r * 3 + 0] - x[c * 3 + 0];
      float dy = x[r * 3 + 1] - x[c * 3 + 1];
      float dz = x[r * 3 + 2] - x[c * 3 + 2];
      dst[256] = dx * dx + dy * dy + dz * dz;
      dst[257] = ea[edge];
    }
  }
  __syncthreads();
  const int e = tid & 31, cg = tid >> 5;
  const int cb = cg * 16;
  float acc[16];
#pragma unroll
  for (int j = 0; j < 16; ++j) acc[j] = b1[cb + j];
  const float* in_row = &in_tile[e * IN1];
  for (int k = 0; k < IN1; ++k) {
    const float a = in_row[k];
    const float4* wp = (const float4*)(W1 + k * HDIM + cb);
    float4 w0 = wp[0], w1 = wp[1], w2 = wp[2], w3 = wp[3];
    acc[0] += a * w0.x; acc[1] += a * w0.y; acc[2] += a * w0.z; acc[3] += a * w0.w;
    acc[4] += a * w1.x; acc[5] += a * w1.y; acc[6] += a * w1.z; acc[7] += a * w1.w;
    acc[8] += a * w2.x; acc[9] += a * w2.y; acc[10] += a * w2.z; acc[11] += a * w2.w;
    acc[12] += a * w3.x; acc[13] += a * w3.y; acc[14] += a * w3.z; acc[15] += a * w3.w;
  }
#pragma unroll
  for (int j = 0; j < 16; ++j) m1[e * 129 + cb + j] = silu_f(acc[j]);
  __syncthreads();
  float acc2[16];
#pragma unroll
  for (int j = 0; j < 16; ++j) acc2[j] = b2[cb + j];
  const float* mrow = &m1[e * 129];
  for (int k = 0; k < HDIM; ++k) {
    const float a = mrow[k];
    const float4* wp = (const float4*)(W2 + k * HDIM + cb);
    float4 w0 = wp[0], w1 = wp[1], w2 = wp[2], w3 = wp[3];
    acc2[0] += a * w0.x; acc2[1] += a * w0.y; acc2[2] += a * w0.z; acc2[3] += a * w0.w;
    acc2[4] += a * w1.x; acc2[5] += a * w1.y; acc2[6] += a * w1.z; acc2[7] += a * w1.w;
    acc2[8] += a * w2.x; acc2[9] += a * w2.y; acc2[10] += a * w2.z; acc2[11] += a * w2.w;
    acc2[12] += a * w3.x; acc2[13] += a * w3.y; acc2[14] += a * w3.z; acc2[15] += a * w3.w;
  }
  const int r = rowidx[e];
  float* ap = agg + (size_t)r * HDIM + cb;
#pragma unroll
  for (int j = 0; j < 16; ++j) atomicAdd(&ap[j], silu_f(acc2[j]));
}

// ---------------- node update: h += rownorm([h|agg/100]@enc)@Wqd + dec_b --
__global__ __launch_bounds__(256) void node_kernel(
    float* __restrict__ hio, const float* __restrict__ agg,
    const float* __restrict__ encw, const float* __restrict__ encb,
    const float* __restrict__ wqd, const float* __restrict__ decb) {
  __shared__ float in2[32 * 257];
  __shared__ float qn[32 * 129];
  __shared__ float partials[256];
  const int tid = threadIdx.x;
  const int n0 = blockIdx.x * 32;
  {
    const int e = tid >> 3, j = tid & 7;
    const int node = n0 + e;
    if (node < N_NODES) {
      const float4* hr = (const float4*)(hio + (size_t)node * HDIM);
      const float4* ar = (const float4*)(agg + (size_t)node * HDIM);
      float* dst = &in2[e * 257];
#pragma unroll
      for (int t = 0; t < 4; ++t) {
        const int c4 = j + t * 8;
        float4 v = hr[c4];
        dst[c4 * 4 + 0] = v.x; dst[c4 * 4 + 1] = v.y;
        dst[c4 * 4 + 2] = v.z; dst[c4 * 4 + 3] = v.w;
        float4 w = ar[c4];
        dst[128 + c4 * 4 + 0] = w.x * 0.01f; dst[128 + c4 * 4 + 1] = w.y * 0.01f;
        dst[128 + c4 * 4 + 2] = w.z * 0.01f; dst[128 + c4 * 4 + 3] = w.w * 0.01f;
      }
    }
  }
  __syncthreads();
  const int e = tid & 31, cg = tid >> 5;
  const int cb = cg * 16;
  const int node = n0 + e;
  const bool valid = node < N_NODES;
  float acc[16];
#pragma unroll
  for (int j = 0; j < 16; ++j) acc[j] = encb[cb + j];
  const float* in_row = &in2[e * 257];
  for (int k = 0; k < 256; ++k) {
    const float a = in_row[k];
    const float4* wp = (const float4*)(encw + k * HDIM + cb);
    float4 w0 = wp[0], w1 = wp[1], w2 = wp[2], w3 = wp[3];
    acc[0] += a * w0.x; acc[1] += a * w0.y; acc[2] += a * w0.z; acc[3] += a * w0.w;
    acc[4] += a * w1.x; acc[5] += a * w1.y; acc[6] += a * w1.z; acc[7] += a * w1.w;
    acc[8] += a * w2.x; acc[9] += a * w2.y; acc[10] += a * w2.z; acc[11] += a * w2.w;
    acc[12] += a * w3.x; acc[13] += a * w3.y; acc[14] += a * w3.z; acc[15] += a * w3.w;
  }
  float ss = 0.f;
#pragma unroll
  for (int j = 0; j < 16; ++j) {
    ss += acc[j] * acc[j];
    qn[e * 129 + cb + j] = acc[j];
  }
  partials[cg * 32 + e] = ss;
  __syncthreads();
  float sum = 0.f;
#pragma unroll
  for (int g = 0; g < 8; ++g) sum += partials[g * 32 + e];
  const float inv = 1.0f / sqrtf(sum + 1e-12f);
  float acc2[16];
#pragma unroll
  for (int j = 0; j < 16; ++j) acc2[j] = 0.f;
  const float* qrow = &qn[e * 129];
  for (int k = 0; k < 128; ++k) {
    const float a = qrow[k];
    const float4* wp = (const float4*)(wqd + k * HDIM + cb);
    float4 w0 = wp[0], w1 = wp[1], w2 = wp[2], w3 = wp[3];
    acc2[0] += a * w0.x; acc2[1] += a * w0.y; acc2[2] += a * w0.z; acc2[3] += a * w0.w;
    acc2[4] += a * w1.x; acc2[5] += a * w1.y; acc2[6] += a * w1.z; acc2[7] += a * w1.w;
    acc2[8] += a * w2.x; acc2[9] += a * w2.y; acc2[10] += a * w2.z; acc2[11] += a * w2.w;
    acc2[12] += a * w3.x; acc2[13] += a * w3.y; acc2[14] += a * w3.z; acc2[15] += a * w3.w;
  }
  if (valid) {
#pragma unroll
    for (int j = 0; j < 16; ++j)
      hio[(size_t)node * HDIM + cb + j] = in_row[cb + j] + acc2[j] * inv + decb[cb + j];
  }
}

// ---------------- coordinate head: x += segsum(coord_diff * t)/100 -------
__global__ __launch_bounds__(256) void coord_kernel(
    const float* __restrict__ h, const int* __restrict__ ei,
    const float* __restrict__ x, const float* __restrict__ ea,
    const float* __restrict__ W1, const float* __restrict__ b1,
    const float* __restrict__ W2, const float* __restrict__ b2,
    const float* __restrict__ w3, float* __restrict__ xout) {
  __shared__ float in_tile[32 * IN1];
  __shared__ float t1[32 * 129];
  __shared__ float cd[32 * 3];
  __shared__ int rowidx[32];
  __shared__ float partials[256];
  const int tid = threadIdx.x;
  const int e0 = blockIdx.x * 32;
  {
    const int e = tid >> 3, j = tid & 7;
    const int edge = e0 + e;
    const int r = ei[edge], c = ei[N_EDGES + edge];
    if (j == 0) rowidx[e] = r;
    const float4* hr = (const float4*)(h + (size_t)r * HDIM);
    const float4* hc = (const float4*)(h + (size_t)c * HDIM);
    float* dst = &in_tile[e * IN1];
#pragma unroll
    for (int t = 0; t < 4; ++t) {
      const int c4 = j + t * 8;
      float4 v = hr[c4];
      dst[c4 * 4 + 0] = v.x; dst[c4 * 4 + 1] = v.y;
      dst[c4 * 4 + 2] = v.z; dst[c4 * 4 + 3] = v.w;
      float4 w = hc[c4];
      dst[128 + c4 * 4 + 0] = w.x; dst[128 + c4 * 4 + 1] = w.y;
      dst[128 + c4 * 4 + 2] = w.z; dst[128 + c4 * 4 + 3] = w.w;
    }
    if (j == 1) {
      float dx = x[r * 3 + 0] - x[c * 3 + 0];
      float dy = x[r * 3 + 1] - x[c * 3 + 1];
      float dz = x[r * 3 + 2] - x[c * 3 + 2];
      float radial = dx * dx + dy * dy + dz * dz;
      dst[256] = radial;
      dst[257] = ea[edge];
      float s = 1.0f / (sqrtf(radial + 1e-8f) + 1.0f);   // NORM_CONST=1
      cd[e * 3 + 0] = dx * s; cd[e * 3 + 1] = dy * s; cd[e * 3 + 2] = dz * s;
    }
  }
  __syncthreads();
  const int e = tid & 31, cg = tid >> 5;
  const int cb = cg * 16;
  float acc[16];
#pragma unroll
  for (int j = 0; j < 16; ++j) acc[j] = b1[cb + j];
  const float* in_row = &in_tile[e * IN1];
  for (int k = 0; k < IN1; ++k) {
    const float a = in_row[k];
    const float4* wp = (const float4*)(W1 + k * HDIM + cb);
    float4 w0 = wp[0], w1 = wp[1], w2 = wp[2], w3v = wp[3];
    acc[0] += a * w0.x; acc[1] += a * w0.y; acc[2] += a * w0.z; acc[3] += a * w0.w;
    acc[4] += a * w1.x; acc[5] += a * w1.y; acc[6] += a * w1.z; acc[7] += a * w1.w;
    acc[8] += a * w2.x; acc[9] += a * w2.y; acc[10] += a * w2.z; acc[11] += a * w2.w;
    acc[12] += a * w3v.x; acc[13] += a * w3v.y; acc[14] += a * w3v.z; acc[15] += a * w3v.w;
  }
#pragma unroll
  for (int j = 0; j < 16; ++j) t1[e * 129 + cb + j] = silu_f(acc[j]);
  __syncthreads();
  float acc2[16];
#pragma unroll
  for (int j = 0; j < 16; ++j) acc2[j] = b2[cb + j];
  const float* mrow = &t1[e * 129];
  for (int k = 0; k < HDIM; ++k) {
    const float a = mrow[k];
    const float4* wp = (const float4*)(W2 + k * HDIM + cb);
    float4 w0 = wp[0], w1 = wp[1], w2 = wp[2], w3v = wp[3];
    acc2[0] += a * w0.x; acc2[1] += a * w0.y; acc2[2] += a * w0.z; acc2[3] += a * w0.w;
    acc2[4] += a * w1.x; acc2[5] += a * w1.y; acc2[6] += a * w1.z; acc2[7] += a * w1.w;
    acc2[8] += a * w2.x; acc2[9] += a * w2.y; acc2[10] += a * w2.z; acc2[11] += a * w2.w;
    acc2[12] += a * w3v.x; acc2[13] += a * w3v.y; acc2[14] += a * w3v.z; acc2[15] += a * w3v.w;
  }
  float part = 0.f;
#pragma unroll
  for (int j = 0; j < 16; ++j) part += silu_f(acc2[j]) * w3[cb + j];
  partials[cg * 32 + e] = part;
  __syncthreads();
  if (tid < 32) {
    const int ee = tid;
    float t = 0.f;
#pragma unroll
    for (int g = 0; g < 8; ++g) t += partials[g * 32 + ee];
    t *= 0.01f;   // /NORM
    const int r = rowidx[ee];
    atomicAdd(&xout[r * 3 + 0], cd[ee * 3 + 0] * t);
    atomicAdd(&xout[r * 3 + 1], cd[ee * 3 + 1] * t);
    atomicAdd(&xout[r * 3 + 2], cd[ee * 3 + 2] * t);
  }
}

extern "C" void kernel_launch(void* const* d_in, const int* in_sizes, int n_in,
                              void* d_out, int out_size, void* d_ws, size_t ws_size,
                              hipStream_t stream) {
  const float* h     = (const float*)d_in[0];
  const float* x     = (const float*)d_in[1];
  const int*   ei    = (const int*)d_in[2];
  const float* ea    = (const float*)d_in[3];
  const float* e_w1  = (const float*)d_in[4];
  const float* e_b1  = (const float*)d_in[5];
  const float* e_w2  = (const float*)d_in[6];
  const float* e_b2  = (const float*)d_in[7];
  const float* enc_w = (const float*)d_in[8];
  const float* enc_b = (const float*)d_in[9];
  const float* coeffs= (const float*)d_in[10];
  const float* A_re  = (const float*)d_in[11];
  const float* A_im  = (const float*)d_in[12];
  const float* dec_w = (const float*)d_in[13];
  const float* dec_b = (const float*)d_in[14];
  const float* c_w1  = (const float*)d_in[15];
  const float* c_b1  = (const float*)d_in[16];
  const float* c_w2  = (const float*)d_in[17];
  const float* c_b2  = (const float*)d_in[18];
  const float* c_w3  = (const float*)d_in[19];

  float* out = (float*)d_out;
  float* ws  = (float*)d_ws;

  // workspace layout (floats) — total ~33.7 MB
  float*  agg0 = ws;                       // N*128
  float*  agg1 = ws + 3840000;             // N*128
  float2* aug  = (float2*)(ws + 7680000);  // 4 * 128*256 complex
  float2* qm   = (float2*)(ws + 7942144);  // 4 * 128*128 complex
  float2* gkm  = (float2*)(ws + 8073216);  // 4 * 128*128 complex
  float2* njm  = (float2*)(ws + 8204288);  // 4 * 128*128 complex
  float2* um   = (float2*)(ws + 8335360);  // 2 * 128*128 complex
  float*  wqd  = ws + 8400896;             // 2 * 128*128 real
  int*    perm = (int*)(ws + 8433664);     // 128 ints

  // init output (h copy + x copy), zero both agg buffers
  init_out_kernel<<<15000, 256, 0, stream>>>(h, x, out);
  hipMemsetAsync(d_ws, 0, (size_t)2 * 3840000 * sizeof(float), stream);

  // quantum-operator precompute (tiny)
  perm_kernel<<<1, 128, 0, stream>>>(perm);
  build_aug_kernel<<<dim3(128, 4), 256, 0, stream>>>(A_re, A_im, aug);
  gj_kernel<<<4, 1024, 0, stream>>>(aug);
  qmat_kernel<<<dim3(64, 4), 256, 0, stream>>>(A_re, A_im, aug, qm);
  gk_kernel<<<dim3(64, 4), 256, 0, stream>>>(coeffs, gkm);
  nj_kernel<<<dim3(64, 4), 256, 0, stream>>>(qm, gkm, perm, njm);
  compose_kernel<<<dim3(64, 2), 256, 0, stream>>>(njm, um);
  wqd_kernel<<<dim3(64, 2), 256, 0, stream>>>(um, dec_w, wqd);

  // two message-passing layers; h lives in d_out's h region
  for (int l = 0; l < 2; ++l) {
    float* agg = (l == 0) ? agg0 : agg1;
    edge_mlp_kernel<<<15000, 256, 0, stream>>>(
        out, ei, x, ea,
        e_w1 + (size_t)l * IN1 * HDIM, e_b1 + l * HDIM,
        e_w2 + (size_t)l * HDIM * HDIM, e_b2 + l * HDIM, agg);
    node_kernel<<<938, 256, 0, stream>>>(
        out, agg,
        enc_w + (size_t)l * 256 * HDIM, enc_b + l * HDIM,
        wqd + (size_t)l * HDIM * HDIM, dec_b + l * HDIM);
  }

  // coordinate head
  coord_kernel<<<15000, 256, 0, stream>>>(
      out, ei, x, ea, c_w1, c_b1, c_w2, c_b2, c_w3, out + (size_t)N_NODES * HDIM);
}

// Round 2
// 9304.849 us; speedup vs baseline: 1.2763x; 1.2763x over previous
//
#include <hip/hip_runtime.h>
#include <math.h>

#define N_NODES 30000
#define N_EDGES 480000
#define HDIM 128
#define IN1 258   // 2H+2

__device__ __forceinline__ float silu_f(float v) {
  return v / (1.0f + __expf(-v));
}

// ---------------- output init: out = [h | x] ----------------
__global__ void init_out_kernel(const float* __restrict__ h,
                                const float* __restrict__ x,
                                float* __restrict__ out) {
  int idx = blockIdx.x * 256 + threadIdx.x;   // grid exactly covers N*128
  out[idx] = h[idx];
  if (idx < N_NODES * 3) out[N_NODES * HDIM + idx] = x[idx];
}

// ---------------- counting sort of edges by destination row ----------------
__global__ void count_kernel(const int* __restrict__ ei, int* __restrict__ cursor) {
  int e = blockIdx.x * 256 + threadIdx.x;   // grid covers exactly N_EDGES
  atomicAdd(&cursor[ei[e]], 1);
}

__global__ __launch_bounds__(1024) void scan_kernel(int* __restrict__ cursor) {
  __shared__ int sums[1024];
  const int tid = threadIdx.x;
  const int base = tid * 30;
  int local[30];
  int s = 0;
#pragma unroll
  for (int j = 0; j < 30; ++j) {
    int idx = base + j;
    int d = (idx < N_NODES) ? cursor[idx] : 0;
    local[j] = s;
    s += d;
  }
  sums[tid] = s;
  __syncthreads();
  for (int off = 1; off < 1024; off <<= 1) {
    int add = (tid >= off) ? sums[tid - off] : 0;
    __syncthreads();
    sums[tid] += add;
    __syncthreads();
  }
  int excl = (tid == 0) ? 0 : sums[tid - 1];
#pragma unroll
  for (int j = 0; j < 30; ++j) {
    int idx = base + j;
    if (idx < N_NODES) cursor[idx] = excl + local[j];
  }
}

__global__ void fill_kernel(const int* __restrict__ ei, int* __restrict__ cursor,
                            int* __restrict__ elist) {
  int e = blockIdx.x * 256 + threadIdx.x;
  int r = ei[e];
  int pos = atomicAdd(&cursor[r], 1);
  elist[pos] = e;
}

// ---------------- CNOT ring permutation g[c] ----------------
__global__ void perm_kernel(int* __restrict__ g) {
  int i = threadIdx.x;
  int v = i;
  const int cs[7] = {6, 5, 4, 3, 2, 1, 0};
  const int ts[7] = {0, 6, 5, 4, 3, 2, 1};
#pragma unroll
  for (int p = 0; p < 7; ++p) {
    int cb = (v >> (6 - cs[p])) & 1;
    v = v ^ (cb << (6 - ts[p]));
  }
  g[i] = v;
}

// ---------------- build augmented [A_h + iI | I] ----------------
__global__ void build_aug_kernel(const float* __restrict__ Are,
                                 const float* __restrict__ Aim,
                                 float2* __restrict__ aug) {
  int lj = blockIdx.y;
  int r = blockIdx.x;
  int c = threadIdx.x;   // 0..255
  const float* are = Are + (size_t)lj * 16384;
  const float* aim = Aim + (size_t)lj * 16384;
  float2 v;
  if (c < 128) {
    float re = are[r * 128 + c] + are[c * 128 + r];
    float im = aim[r * 128 + c] - aim[c * 128 + r];
    if (c == r) im += 1.0f;
    v = make_float2(re, im);
  } else {
    v = make_float2((c - 128) == r ? 1.0f : 0.0f, 0.0f);
  }
  aug[(size_t)lj * 128 * 256 + r * 256 + c] = v;
}

// ---------------- in-place Gauss-Jordan (no pivoting; Hermitian+iI) ----
__global__ __launch_bounds__(1024) void gj_kernel(float2* __restrict__ augg) {
  float2* M = augg + (size_t)blockIdx.x * 128 * 256;
  __shared__ float2 rowbuf[256];
  __shared__ float2 fbuf[128];
  __shared__ float2 ipiv_s;
  const int tid = threadIdx.x;
  for (int p = 0; p < 128; ++p) {
    if (tid == 0) {
      float2 piv = M[p * 256 + p];
      float d = piv.x * piv.x + piv.y * piv.y;
      ipiv_s = make_float2(piv.x / d, -piv.y / d);
    }
    __syncthreads();
    float2 ip = ipiv_s;
    if (tid < 256) {
      float2 m = M[p * 256 + tid];
      float2 s = make_float2(m.x * ip.x - m.y * ip.y, m.x * ip.y + m.y * ip.x);
      rowbuf[tid] = s;
      M[p * 256 + tid] = s;
    } else if (tid < 384) {
      int r = tid - 256;
      fbuf[r] = (r == p) ? make_float2(0.f, 0.f) : M[r * 256 + p];
    }
    __syncthreads();
    const int c = tid & 255, rg = tid >> 8;   // rg 0..3
    float2 pr = rowbuf[c];
#pragma unroll 4
    for (int rr = 0; rr < 32; ++rr) {
      int r = rg * 32 + rr;
      if (r != p) {
        float2 f = fbuf[r];
        float2 m = M[r * 256 + c];
        m.x -= f.x * pr.x - f.y * pr.y;
        m.y -= f.x * pr.y + f.y * pr.x;
        M[r * 256 + c] = m;
      }
    }
    __syncthreads();
  }
}

// ---------------- q = (A_h - iI) * Binv ----------------
__global__ void qmat_kernel(const float* __restrict__ Are,
                            const float* __restrict__ Aim,
                            const float2* __restrict__ augg,
                            float2* __restrict__ qm) {
  int lj = blockIdx.y;
  int idx = blockIdx.x * 256 + threadIdx.x;
  int r = idx >> 7, c = idx & 127;
  const float* are = Are + (size_t)lj * 16384;
  const float* aim = Aim + (size_t)lj * 16384;
  const float2* binv = augg + (size_t)lj * 128 * 256;
  float2 acc = make_float2(0.f, 0.f);
  for (int k = 0; k < 128; ++k) {
    float re = are[r * 128 + k] + are[k * 128 + r];
    float im = aim[r * 128 + k] - aim[k * 128 + r];
    if (k == r) im -= 1.0f;
    float2 b = binv[k * 256 + 128 + c];
    acc.x += re * b.x - im * b.y;
    acc.y += re * b.y + im * b.x;
  }
  qm[(size_t)lj * 16384 + idx] = acc;
}

// ---------------- Gk = (RY*RX)^(kron 7), elementwise ----------------
__global__ void gk_kernel(const float* __restrict__ coeffs,
                          float2* __restrict__ gkm) {
  int lj = blockIdx.y;
  float a = coeffs[lj * 2 + 0], b = coeffs[lj * 2 + 1];
  float ca = cosf(0.5f * a), sa = sinf(0.5f * a);
  float cb = cosf(0.5f * b), sb = sinf(0.5f * b);
  float2 G[2][2];
  G[0][0] = make_float2(cb * ca, sb * sa);
  G[0][1] = make_float2(-sb * ca, -cb * sa);
  G[1][0] = make_float2(sb * ca, -cb * sa);
  G[1][1] = make_float2(cb * ca, -sb * sa);
  int idx = blockIdx.x * 256 + threadIdx.x;
  int r = idx >> 7, c = idx & 127;
  float2 acc = make_float2(1.f, 0.f);
#pragma unroll
  for (int bit = 6; bit >= 0; --bit) {
    float2 g = G[(r >> bit) & 1][(c >> bit) & 1];
    acc = make_float2(acc.x * g.x - acc.y * g.y, acc.x * g.y + acc.y * g.x);
  }
  gkm[(size_t)lj * 16384 + idx] = acc;
}

// ---------------- N_j[i][c] = sum_k q[k][i] * Gk[g[c]][k] ----------------
__global__ void nj_kernel(const float2* __restrict__ qm,
                          const float2* __restrict__ gkm,
                          const int* __restrict__ g,
                          float2* __restrict__ njm) {
  int lj = blockIdx.y;
  int idx = blockIdx.x * 256 + threadIdx.x;
  int i = idx >> 7, c = idx & 127;
  int gc = g[c];
  const float2* q = qm + (size_t)lj * 16384;
  const float2* gk = gkm + (size_t)lj * 16384;
  float2 acc = make_float2(0.f, 0.f);
  for (int k = 0; k < 128; ++k) {
    float2 qa = q[k * 128 + i];
    float2 gb = gk[gc * 128 + k];
    acc.x += qa.x * gb.x - qa.y * gb.y;
    acc.y += qa.x * gb.y + qa.y * gb.x;
  }
  njm[(size_t)lj * 16384 + idx] = acc;
}

// ---------------- U_l = N_{l,0} @ N_{l,1} ----------------
__global__ void compose_kernel(const float2* __restrict__ njm,
                               float2* __restrict__ um) {
  int l = blockIdx.y;
  int idx = blockIdx.x * 256 + threadIdx.x;
  int i = idx >> 7, c = idx & 127;
  const float2* n0 = njm + (size_t)(l * 2 + 0) * 16384;
  const float2* n1 = njm + (size_t)(l * 2 + 1) * 16384;
  float2 acc = make_float2(0.f, 0.f);
  for (int k = 0; k < 128; ++k) {
    float2 a = n0[i * 128 + k];
    float2 b = n1[k * 128 + c];
    acc.x += a.x * b.x - a.y * b.y;
    acc.y += a.x * b.y + a.y * b.x;
  }
  um[(size_t)l * 16384 + idx] = acc;
}

// ---------------- Wqd_l = Re(U_l) @ dec_w_l ----------------
__global__ void wqd_kernel(const float2* __restrict__ um,
                           const float* __restrict__ decw,
                           float* __restrict__ wqd) {
  int l = blockIdx.y;
  int idx = blockIdx.x * 256 + threadIdx.x;
  int i = idx >> 7, c = idx & 127;
  const float2* u = um + (size_t)l * 16384;
  const float* dw = decw + (size_t)l * 16384;
  float acc = 0.f;
  for (int k = 0; k < 128; ++k) acc += u[i * 128 + k].x * dw[k * 128 + c];
  wqd[(size_t)l * 16384 + idx] = acc;
}

// ---------------- edge MLP over row-sorted edges + segmented scatter ------
// 32 edges/block (CSR order), 256 threads: thread (e = tid&31, cg = tid>>5)
// computes 16 output cols for its edge. Tile rows are sorted, so a
// per-tile segmented reduction leaves ~3 leader atomics per tile instead
// of 32 (atomics write through L2 at 32B/op — that was R0's bottleneck).
__global__ __launch_bounds__(256) void edge_mlp_sorted_kernel(
    const float* __restrict__ h, const int* __restrict__ ei,
    const float* __restrict__ x, const float* __restrict__ ea,
    const int* __restrict__ elist,
    const float* __restrict__ W1, const float* __restrict__ b1,
    const float* __restrict__ W2, const float* __restrict__ b2,
    float* __restrict__ agg) {
  __shared__ float in_tile[32 * IN1];   // stride 258: 2-way LDS alias, free
  __shared__ float m1[32 * 129];        // stride 129: conflict-free
  __shared__ int rows[32];
  const int tid = threadIdx.x;
  const int i0 = blockIdx.x * 32;
  {
    const int e = tid >> 3, j = tid & 7;
    const int edge = elist[i0 + e];
    const int r = ei[edge], c = ei[N_EDGES + edge];
    if (j == 0) rows[e] = r;
    const float4* hr = (const float4*)(h + (size_t)r * HDIM);
    const float4* hc = (const float4*)(h + (size_t)c * HDIM);
    float* dst = &in_tile[e * IN1];
#pragma unroll
    for (int t = 0; t < 4; ++t) {
      const int c4 = j + t * 8;
      float4 v = hr[c4];
      dst[c4 * 4 + 0] = v.x; dst[c4 * 4 + 1] = v.y;
      dst[c4 * 4 + 2] = v.z; dst[c4 * 4 + 3] = v.w;
      float4 w = hc[c4];
      dst[128 + c4 * 4 + 0] = w.x; dst[128 + c4 * 4 + 1] = w.y;
      dst[128 + c4 * 4 + 2] = w.z; dst[128 + c4 * 4 + 3] = w.w;
    }
    if (j == 1) {
      float dx = x[r * 3 + 0] - x[c * 3 + 0];
      float dy = x[r * 3 + 1] - x[c * 3 + 1];
      float dz = x[r * 3 + 2] - x[c * 3 + 2];
      dst[256] = dx * dx + dy * dy + dz * dz;
      dst[257] = ea[edge];
    }
  }
  __syncthreads();
  const int e = tid & 31, cg = tid >> 5;
  const int cb = cg * 16;
  float acc[16];
#pragma unroll
  for (int j = 0; j < 16; ++j) acc[j] = b1[cb + j];
  const float* in_row = &in_tile[e * IN1];
  for (int k = 0; k < IN1; ++k) {
    const float a = in_row[k];
    const float4* wp = (const float4*)(W1 + k * HDIM + cb);
    float4 w0 = wp[0], w1 = wp[1], w2 = wp[2], w3 = wp[3];
    acc[0] += a * w0.x; acc[1] += a * w0.y; acc[2] += a * w0.z; acc[3] += a * w0.w;
    acc[4] += a * w1.x; acc[5] += a * w1.y; acc[6] += a * w1.z; acc[7] += a * w1.w;
    acc[8] += a * w2.x; acc[9] += a * w2.y; acc[10] += a * w2.z; acc[11] += a * w2.w;
    acc[12] += a * w3.x; acc[13] += a * w3.y; acc[14] += a * w3.z; acc[15] += a * w3.w;
  }
#pragma unroll
  for (int j = 0; j < 16; ++j) m1[e * 129 + cb + j] = silu_f(acc[j]);
  __syncthreads();
  float acc2[16];
#pragma unroll
  for (int j = 0; j < 16; ++j) acc2[j] = b2[cb + j];
  const float* mrow = &m1[e * 129];
  for (int k = 0; k < HDIM; ++k) {
    const float a = mrow[k];
    const float4* wp = (const float4*)(W2 + k * HDIM + cb);
    float4 w0 = wp[0], w1 = wp[1], w2 = wp[2], w3 = wp[3];
    acc2[0] += a * w0.x; acc2[1] += a * w0.y; acc2[2] += a * w0.z; acc2[3] += a * w0.w;
    acc2[4] += a * w1.x; acc2[5] += a * w1.y; acc2[6] += a * w1.z; acc2[7] += a * w1.w;
    acc2[8] += a * w2.x; acc2[9] += a * w2.y; acc2[10] += a * w2.z; acc2[11] += a * w2.w;
    acc2[12] += a * w3.x; acc2[13] += a * w3.y; acc2[14] += a * w3.z; acc2[15] += a * w3.w;
  }
  __syncthreads();   // all m1 reads done; reuse m1 as message tile
#pragma unroll
  for (int j = 0; j < 16; ++j) m1[e * 129 + cb + j] = silu_f(acc2[j]);
  __syncthreads();
  // segmented reduction over sorted rows; leaders only issue atomics
  const int r_e = rows[e];
  const bool leader = (e == 0) || (rows[e - 1] != r_e);
  if (leader) {
    float sum[16];
#pragma unroll
    for (int j = 0; j < 16; ++j) sum[j] = m1[e * 129 + cb + j];
    int f = e + 1;
    while (f < 32 && rows[f] == r_e) {
#pragma unroll
      for (int j = 0; j < 16; ++j) sum[j] += m1[f * 129 + cb + j];
      ++f;
    }
    float* ap = agg + (size_t)r_e * HDIM + cb;
#pragma unroll
    for (int j = 0; j < 16; ++j) atomicAdd(&ap[j], sum[j]);
  }
}

// ---------------- node update: h += rownorm([h|agg/100]@enc)@Wqd + dec_b --
__global__ __launch_bounds__(256) void node_kernel(
    float* __restrict__ hio, const float* __restrict__ agg,
    const float* __restrict__ encw, const float* __restrict__ encb,
    const float* __restrict__ wqd, const float* __restrict__ decb) {
  __shared__ float in2[32 * 257];
  __shared__ float qn[32 * 129];
  __shared__ float partials[256];
  const int tid = threadIdx.x;
  const int n0 = blockIdx.x * 32;
  {
    const int e = tid >> 3, j = tid & 7;
    const int node = n0 + e;
    if (node < N_NODES) {
      const float4* hr = (const float4*)(hio + (size_t)node * HDIM);
      const float4* ar = (const float4*)(agg + (size_t)node * HDIM);
      float* dst = &in2[e * 257];
#pragma unroll
      for (int t = 0; t < 4; ++t) {
        const int c4 = j + t * 8;
        float4 v = hr[c4];
        dst[c4 * 4 + 0] = v.x; dst[c4 * 4 + 1] = v.y;
        dst[c4 * 4 + 2] = v.z; dst[c4 * 4 + 3] = v.w;
        float4 w = ar[c4];
        dst[128 + c4 * 4 + 0] = w.x * 0.01f; dst[128 + c4 * 4 + 1] = w.y * 0.01f;
        dst[128 + c4 * 4 + 2] = w.z * 0.01f; dst[128 + c4 * 4 + 3] = w.w * 0.01f;
      }
    }
  }
  __syncthreads();
  const int e = tid & 31, cg = tid >> 5;
  const int cb = cg * 16;
  const int node = n0 + e;
  const bool valid = node < N_NODES;
  float acc[16];
#pragma unroll
  for (int j = 0; j < 16; ++j) acc[j] = encb[cb + j];
  const float* in_row = &in2[e * 257];
  for (int k = 0; k < 256; ++k) {
    const float a = in_row[k];
    const float4* wp = (const float4*)(encw + k * HDIM + cb);
    float4 w0 = wp[0], w1 = wp[1], w2 = wp[2], w3 = wp[3];
    acc[0] += a * w0.x; acc[1] += a * w0.y; acc[2] += a * w0.z; acc[3] += a * w0.w;
    acc[4] += a * w1.x; acc[5] += a * w1.y; acc[6] += a * w1.z; acc[7] += a * w1.w;
    acc[8] += a * w2.x; acc[9] += a * w2.y; acc[10] += a * w2.z; acc[11] += a * w2.w;
    acc[12] += a * w3.x; acc[13] += a * w3.y; acc[14] += a * w3.z; acc[15] += a * w3.w;
  }
  float ss = 0.f;
#pragma unroll
  for (int j = 0; j < 16; ++j) {
    ss += acc[j] * acc[j];
    qn[e * 129 + cb + j] = acc[j];
  }
  partials[cg * 32 + e] = ss;
  __syncthreads();
  float sum = 0.f;
#pragma unroll
  for (int g = 0; g < 8; ++g) sum += partials[g * 32 + e];
  const float inv = 1.0f / sqrtf(sum + 1e-12f);
  float acc2[16];
#pragma unroll
  for (int j = 0; j < 16; ++j) acc2[j] = 0.f;
  const float* qrow = &qn[e * 129];
  for (int k = 0; k < 128; ++k) {
    const float a = qrow[k];
    const float4* wp = (const float4*)(wqd + k * HDIM + cb);
    float4 w0 = wp[0], w1 = wp[1], w2 = wp[2], w3 = wp[3];
    acc2[0] += a * w0.x; acc2[1] += a * w0.y; acc2[2] += a * w0.z; acc2[3] += a * w0.w;
    acc2[4] += a * w1.x; acc2[5] += a * w1.y; acc2[6] += a * w1.z; acc2[7] += a * w1.w;
    acc2[8] += a * w2.x; acc2[9] += a * w2.y; acc2[10] += a * w2.z; acc2[11] += a * w2.w;
    acc2[12] += a * w3.x; acc2[13] += a * w3.y; acc2[14] += a * w3.z; acc2[15] += a * w3.w;
  }
  if (valid) {
#pragma unroll
    for (int j = 0; j < 16; ++j)
      hio[(size_t)node * HDIM + cb + j] = in_row[cb + j] + acc2[j] * inv + decb[cb + j];
  }
}

// ---------------- coordinate head over sorted edges -----------------------
__global__ __launch_bounds__(256) void coord_sorted_kernel(
    const float* __restrict__ h, const int* __restrict__ ei,
    const float* __restrict__ x, const float* __restrict__ ea,
    const int* __restrict__ elist,
    const float* __restrict__ W1, const float* __restrict__ b1,
    const float* __restrict__ W2, const float* __restrict__ b2,
    const float* __restrict__ w3, float* __restrict__ xout) {
  __shared__ float in_tile[32 * IN1];
  __shared__ float t1[32 * 129];
  __shared__ float cd[32 * 3];
  __shared__ float tvals[32];
  __shared__ int rows[32];
  __shared__ float partials[256];
  const int tid = threadIdx.x;
  const int i0 = blockIdx.x * 32;
  {
    const int e = tid >> 3, j = tid & 7;
    const int edge = elist[i0 + e];
    const int r = ei[edge], c = ei[N_EDGES + edge];
    if (j == 0) rows[e] = r;
    const float4* hr = (const float4*)(h + (size_t)r * HDIM);
    const float4* hc = (const float4*)(h + (size_t)c * HDIM);
    float* dst = &in_tile[e * IN1];
#pragma unroll
    for (int t = 0; t < 4; ++t) {
      const int c4 = j + t * 8;
      float4 v = hr[c4];
      dst[c4 * 4 + 0] = v.x; dst[c4 * 4 + 1] = v.y;
      dst[c4 * 4 + 2] = v.z; dst[c4 * 4 + 3] = v.w;
      float4 w = hc[c4];
      dst[128 + c4 * 4 + 0] = w.x; dst[128 + c4 * 4 + 1] = w.y;
      dst[128 + c4 * 4 + 2] = w.z; dst[128 + c4 * 4 + 3] = w.w;
    }
    if (j == 1) {
      float dx = x[r * 3 + 0] - x[c * 3 + 0];
      float dy = x[r * 3 + 1] - x[c * 3 + 1];
      float dz = x[r * 3 + 2] - x[c * 3 + 2];
      float radial = dx * dx + dy * dy + dz * dz;
      dst[256] = radial;
      dst[257] = ea[edge];
      float s = 1.0f / (sqrtf(radial + 1e-8f) + 1.0f);   // NORM_CONST=1
      cd[e * 3 + 0] = dx * s; cd[e * 3 + 1] = dy * s; cd[e * 3 + 2] = dz * s;
    }
  }
  __syncthreads();
  const int e = tid & 31, cg = tid >> 5;
  const int cb = cg * 16;
  float acc[16];
#pragma unroll
  for (int j = 0; j < 16; ++j) acc[j] = b1[cb + j];
  const float* in_row = &in_tile[e * IN1];
  for (int k = 0; k < IN1; ++k) {
    const float a = in_row[k];
    const float4* wp = (const float4*)(W1 + k * HDIM + cb);
    float4 w0 = wp[0], w1 = wp[1], w2 = wp[2], w3v = wp[3];
    acc[0] += a * w0.x; acc[1] += a * w0.y; acc[2] += a * w0.z; acc[3] += a * w0.w;
    acc[4] += a * w1.x; acc[5] += a * w1.y; acc[6] += a * w1.z; acc[7] += a * w1.w;
    acc[8] += a * w2.x; acc[9] += a * w2.y; acc[10] += a * w2.z; acc[11] += a * w2.w;
    acc[12] += a * w3v.x; acc[13] += a * w3v.y; acc[14] += a * w3v.z; acc[15] += a * w3v.w;
  }
#pragma unroll
  for (int j = 0; j < 16; ++j) t1[e * 129 + cb + j] = silu_f(acc[j]);
  __syncthreads();
  float acc2[16];
#pragma unroll
  for (int j = 0; j < 16; ++j) acc2[j] = b2[cb + j];
  const float* mrow = &t1[e * 129];
  for (int k = 0; k < HDIM; ++k) {
    const float a = mrow[k];
    const float4* wp = (const float4*)(W2 + k * HDIM + cb);
    float4 w0 = wp[0], w1 = wp[1], w2 = wp[2], w3v = wp[3];
    acc2[0] += a * w0.x; acc2[1] += a * w0.y; acc2[2] += a * w0.z; acc2[3] += a * w0.w;
    acc2[4] += a * w1.x; acc2[5] += a * w1.y; acc2[6] += a * w1.z; acc2[7] += a * w1.w;
    acc2[8] += a * w2.x; acc2[9] += a * w2.y; acc2[10] += a * w2.z; acc2[11] += a * w2.w;
    acc2[12] += a * w3v.x; acc2[13] += a * w3v.y; acc2[14] += a * w3v.z; acc2[15] += a * w3v.w;
  }
  float part = 0.f;
#pragma unroll
  for (int j = 0; j < 16; ++j) part += silu_f(acc2[j]) * w3[cb + j];
  partials[cg * 32 + e] = part;
  __syncthreads();
  if (tid < 32) {
    const int ee = tid;
    float t = 0.f;
#pragma unroll
    for (int g = 0; g < 8; ++g) t += partials[g * 32 + ee];
    tvals[ee] = t * 0.01f;   // /NORM
  }
  __syncthreads();
  if (tid < 32) {
    const int ee = tid;
    const int r_e = rows[ee];
    const bool leader = (ee == 0) || (rows[ee - 1] != r_e);
    if (leader) {
      float sx = cd[ee * 3 + 0] * tvals[ee];
      float sy = cd[ee * 3 + 1] * tvals[ee];
      float sz = cd[ee * 3 + 2] * tvals[ee];
      int f = ee + 1;
      while (f < 32 && rows[f] == r_e) {
        sx += cd[f * 3 + 0] * tvals[f];
        sy += cd[f * 3 + 1] * tvals[f];
        sz += cd[f * 3 + 2] * tvals[f];
        ++f;
      }
      atomicAdd(&xout[r_e * 3 + 0], sx);
      atomicAdd(&xout[r_e * 3 + 1], sy);
      atomicAdd(&xout[r_e * 3 + 2], sz);
    }
  }
}

extern "C" void kernel_launch(void* const* d_in, const int* in_sizes, int n_in,
                              void* d_out, int out_size, void* d_ws, size_t ws_size,
                              hipStream_t stream) {
  const float* h     = (const float*)d_in[0];
  const float* x     = (const float*)d_in[1];
  const int*   ei    = (const int*)d_in[2];
  const float* ea    = (const float*)d_in[3];
  const float* e_w1  = (const float*)d_in[4];
  const float* e_b1  = (const float*)d_in[5];
  const float* e_w2  = (const float*)d_in[6];
  const float* e_b2  = (const float*)d_in[7];
  const float* enc_w = (const float*)d_in[8];
  const float* enc_b = (const float*)d_in[9];
  const float* coeffs= (const float*)d_in[10];
  const float* A_re  = (const float*)d_in[11];
  const float* A_im  = (const float*)d_in[12];
  const float* dec_w = (const float*)d_in[13];
  const float* dec_b = (const float*)d_in[14];
  const float* c_w1  = (const float*)d_in[15];
  const float* c_b1  = (const float*)d_in[16];
  const float* c_w2  = (const float*)d_in[17];
  const float* c_b2  = (const float*)d_in[18];
  const float* c_w3  = (const float*)d_in[19];

  float* out = (float*)d_out;
  float* ws  = (float*)d_ws;

  // workspace layout (floats) — total ~20.4 MB
  float*  agg    = ws;                        // N*128 (reused per layer)
  float2* aug    = (float2*)(ws + 3840000);   // 4 * 128*256 complex
  float2* qm     = (float2*)(ws + 4102144);   // 4 * 128*128 complex
  float2* gkm    = (float2*)(ws + 4233216);   // 4 * 128*128 complex
  float2* njm    = (float2*)(ws + 4364288);   // 4 * 128*128 complex
  float2* um     = (float2*)(ws + 4495360);   // 2 * 128*128 complex
  float*  wqd    = ws + 4560896;              // 2 * 128*128 real
  int*    perm   = (int*)(ws + 4593664);      // 128 ints
  int*    cursor = (int*)(ws + 4593792);      // N ints
  int*    elist  = (int*)(ws + 4623792);      // E ints

  // init output (h copy + x copy)
  init_out_kernel<<<15000, 256, 0, stream>>>(h, x, out);

  // counting sort of edges by destination row
  hipMemsetAsync(cursor, 0, N_NODES * sizeof(int), stream);
  count_kernel<<<1875, 256, 0, stream>>>(ei, cursor);
  scan_kernel<<<1, 1024, 0, stream>>>(cursor);
  fill_kernel<<<1875, 256, 0, stream>>>(ei, cursor, elist);

  // quantum-operator precompute (tiny)
  perm_kernel<<<1, 128, 0, stream>>>(perm);
  build_aug_kernel<<<dim3(128, 4), 256, 0, stream>>>(A_re, A_im, aug);
  gj_kernel<<<4, 1024, 0, stream>>>(aug);
  qmat_kernel<<<dim3(64, 4), 256, 0, stream>>>(A_re, A_im, aug, qm);
  gk_kernel<<<dim3(64, 4), 256, 0, stream>>>(coeffs, gkm);
  nj_kernel<<<dim3(64, 4), 256, 0, stream>>>(qm, gkm, perm, njm);
  compose_kernel<<<dim3(64, 2), 256, 0, stream>>>(njm, um);
  wqd_kernel<<<dim3(64, 2), 256, 0, stream>>>(um, dec_w, wqd);

  // two message-passing layers; h lives in d_out's h region
  for (int l = 0; l < 2; ++l) {
    hipMemsetAsync(agg, 0, (size_t)N_NODES * HDIM * sizeof(float), stream);
    edge_mlp_sorted_kernel<<<15000, 256, 0, stream>>>(
        out, ei, x, ea, elist,
        e_w1 + (size_t)l * IN1 * HDIM, e_b1 + l * HDIM,
        e_w2 + (size_t)l * HDIM * HDIM, e_b2 + l * HDIM, agg);
    node_kernel<<<938, 256, 0, stream>>>(
        out, agg,
        enc_w + (size_t)l * 256 * HDIM, enc_b + l * HDIM,
        wqd + (size_t)l * HDIM * HDIM, dec_b + l * HDIM);
  }

  // coordinate head
  coord_sorted_kernel<<<15000, 256, 0, stream>>>(
      out, ei, x, ea, elist, c_w1, c_b1, c_w2, c_b2, c_w3,
      out + (size_t)N_NODES * HDIM);
}

// Round 3
// 2460.334 us; speedup vs baseline: 4.8269x; 3.7819x over previous
//
#include <hip/hip_runtime.h>
#include <math.h>

#define N_NODES 30000
#define N_EDGES 480000
#define HDIM 128
#define EPB 64        // edges (or nodes) per MFMA block
#define AS 296        // A-tile row stride (bf16): 288 K-pad + 8 (592 B, 16B-aligned, ~2-way banks)
#define NAS 264       // node A-tile row stride (bf16): K=256 + 8
#define MS 136        // m1 row stride (bf16) / m2 stride (f32): 272 B, 16B-aligned

typedef __attribute__((ext_vector_type(8))) short short8b;
typedef __attribute__((ext_vector_type(4))) float f32x4;

__device__ __forceinline__ float silu_f(float v) {
  return v / (1.0f + __expf(-v));
}

__device__ __forceinline__ unsigned short f2bf(float f) {
  unsigned int u = __float_as_uint(f);
  unsigned int r = u + 0x7fffu + ((u >> 16) & 1u);
  return (unsigned short)(r >> 16);
}

// ---------------- output init: out = [h | x] ----------------
__global__ void init_out_kernel(const float* __restrict__ h,
                                const float* __restrict__ x,
                                float* __restrict__ out) {
  int idx = blockIdx.x * 256 + threadIdx.x;
  out[idx] = h[idx];
  if (idx < N_NODES * 3) out[N_NODES * HDIM + idx] = x[idx];
}

// ---------------- h (fp32) -> hbf (bf16), vectorized x4 ----------------
__global__ void h_to_bf_kernel(const float* __restrict__ h,
                               ushort* __restrict__ hbf) {
  int idx = blockIdx.x * 256 + threadIdx.x;   // covers N*128/4
  float4 v = ((const float4*)h)[idx];
  ushort4 o;
  o.x = f2bf(v.x); o.y = f2bf(v.y); o.z = f2bf(v.z); o.w = f2bf(v.w);
  ((ushort4*)hbf)[idx] = o;
}

// ---------------- weight convert: W[K][128] fp32 -> [KT][128][32] bf16 ----
__global__ void convert_w_kernel(const float* __restrict__ W,
                                 ushort* __restrict__ dst, int Kreal, int KT) {
  int idx = blockIdx.x * 256 + threadIdx.x;
  if (idx >= KT * 4096) return;
  int kt = idx >> 12, rem = idx & 4095, n = rem >> 5, kk = rem & 31;
  int k = kt * 32 + kk;
  float v = (k < Kreal) ? W[(size_t)k * HDIM + n] : 0.0f;
  dst[idx] = f2bf(v);
}

// ---------------- counting sort of edges by destination row ----------------
__global__ void count_kernel(const int* __restrict__ ei, int* __restrict__ cursor) {
  int e = blockIdx.x * 256 + threadIdx.x;
  atomicAdd(&cursor[ei[e]], 1);
}

__global__ __launch_bounds__(1024) void scan_kernel(int* __restrict__ cursor) {
  __shared__ int sums[1024];
  const int tid = threadIdx.x;
  const int base = tid * 30;
  int local[30];
  int s = 0;
#pragma unroll
  for (int j = 0; j < 30; ++j) {
    int idx = base + j;
    int d = (idx < N_NODES) ? cursor[idx] : 0;
    local[j] = s;
    s += d;
  }
  sums[tid] = s;
  __syncthreads();
  for (int off = 1; off < 1024; off <<= 1) {
    int add = (tid >= off) ? sums[tid - off] : 0;
    __syncthreads();
    sums[tid] += add;
    __syncthreads();
  }
  int excl = (tid == 0) ? 0 : sums[tid - 1];
#pragma unroll
  for (int j = 0; j < 30; ++j) {
    int idx = base + j;
    if (idx < N_NODES) cursor[idx] = excl + local[j];
  }
}

__global__ void fill_kernel(const int* __restrict__ ei, int* __restrict__ cursor,
                            int* __restrict__ elist) {
  int e = blockIdx.x * 256 + threadIdx.x;
  int r = ei[e];
  int pos = atomicAdd(&cursor[r], 1);
  elist[pos] = e;
}

// ---------------- CNOT ring permutation ----------------
__global__ void perm_kernel(int* __restrict__ g) {
  int i = threadIdx.x;
  int v = i;
  const int cs[7] = {6, 5, 4, 3, 2, 1, 0};
  const int ts[7] = {0, 6, 5, 4, 3, 2, 1};
#pragma unroll
  for (int p = 0; p < 7; ++p) {
    int cb = (v >> (6 - cs[p])) & 1;
    v = v ^ (cb << (6 - ts[p]));
  }
  g[i] = v;
}

// ---------------- build augmented [A_h + iI | I] ----------------
__global__ void build_aug_kernel(const float* __restrict__ Are,
                                 const float* __restrict__ Aim,
                                 float2* __restrict__ aug) {
  int lj = blockIdx.y;
  int r = blockIdx.x;
  int c = threadIdx.x;
  const float* are = Are + (size_t)lj * 16384;
  const float* aim = Aim + (size_t)lj * 16384;
  float2 v;
  if (c < 128) {
    float re = are[r * 128 + c] + are[c * 128 + r];
    float im = aim[r * 128 + c] - aim[c * 128 + r];
    if (c == r) im += 1.0f;
    v = make_float2(re, im);
  } else {
    v = make_float2((c - 128) == r ? 1.0f : 0.0f, 0.0f);
  }
  aug[(size_t)lj * 128 * 256 + r * 256 + c] = v;
}

// ---------------- in-place Gauss-Jordan (Hermitian+iI, no pivoting) ----
__global__ __launch_bounds__(1024) void gj_kernel(float2* __restrict__ augg) {
  float2* M = augg + (size_t)blockIdx.x * 128 * 256;
  __shared__ float2 rowbuf[256];
  __shared__ float2 fbuf[128];
  __shared__ float2 ipiv_s;
  const int tid = threadIdx.x;
  for (int p = 0; p < 128; ++p) {
    if (tid == 0) {
      float2 piv = M[p * 256 + p];
      float d = piv.x * piv.x + piv.y * piv.y;
      ipiv_s = make_float2(piv.x / d, -piv.y / d);
    }
    __syncthreads();
    float2 ip = ipiv_s;
    if (tid < 256) {
      float2 m = M[p * 256 + tid];
      float2 s = make_float2(m.x * ip.x - m.y * ip.y, m.x * ip.y + m.y * ip.x);
      rowbuf[tid] = s;
      M[p * 256 + tid] = s;
    } else if (tid < 384) {
      int r = tid - 256;
      fbuf[r] = (r == p) ? make_float2(0.f, 0.f) : M[r * 256 + p];
    }
    __syncthreads();
    const int c = tid & 255, rg = tid >> 8;
    float2 pr = rowbuf[c];
#pragma unroll 4
    for (int rr = 0; rr < 32; ++rr) {
      int r = rg * 32 + rr;
      if (r != p) {
        float2 f = fbuf[r];
        float2 m = M[r * 256 + c];
        m.x -= f.x * pr.x - f.y * pr.y;
        m.y -= f.x * pr.y + f.y * pr.x;
        M[r * 256 + c] = m;
      }
    }
    __syncthreads();
  }
}

// ---------------- q = (A_h - iI) * Binv ----------------
__global__ void qmat_kernel(const float* __restrict__ Are,
                            const float* __restrict__ Aim,
                            const float2* __restrict__ augg,
                            float2* __restrict__ qm) {
  int lj = blockIdx.y;
  int idx = blockIdx.x * 256 + threadIdx.x;
  int r = idx >> 7, c = idx & 127;
  const float* are = Are + (size_t)lj * 16384;
  const float* aim = Aim + (size_t)lj * 16384;
  const float2* binv = augg + (size_t)lj * 128 * 256;
  float2 acc = make_float2(0.f, 0.f);
  for (int k = 0; k < 128; ++k) {
    float re = are[r * 128 + k] + are[k * 128 + r];
    float im = aim[r * 128 + k] - aim[k * 128 + r];
    if (k == r) im -= 1.0f;
    float2 b = binv[k * 256 + 128 + c];
    acc.x += re * b.x - im * b.y;
    acc.y += re * b.y + im * b.x;
  }
  qm[(size_t)lj * 16384 + idx] = acc;
}

// ---------------- Gk = (RY*RX)^(kron 7) ----------------
__global__ void gk_kernel(const float* __restrict__ coeffs,
                          float2* __restrict__ gkm) {
  int lj = blockIdx.y;
  float a = coeffs[lj * 2 + 0], b = coeffs[lj * 2 + 1];
  float ca = cosf(0.5f * a), sa = sinf(0.5f * a);
  float cb = cosf(0.5f * b), sb = sinf(0.5f * b);
  float2 G[2][2];
  G[0][0] = make_float2(cb * ca, sb * sa);
  G[0][1] = make_float2(-sb * ca, -cb * sa);
  G[1][0] = make_float2(sb * ca, -cb * sa);
  G[1][1] = make_float2(cb * ca, -sb * sa);
  int idx = blockIdx.x * 256 + threadIdx.x;
  int r = idx >> 7, c = idx & 127;
  float2 acc = make_float2(1.f, 0.f);
#pragma unroll
  for (int bit = 6; bit >= 0; --bit) {
    float2 g = G[(r >> bit) & 1][(c >> bit) & 1];
    acc = make_float2(acc.x * g.x - acc.y * g.y, acc.x * g.y + acc.y * g.x);
  }
  gkm[(size_t)lj * 16384 + idx] = acc;
}

// ---------------- N_j[i][c] = sum_k q[k][i] * Gk[g[c]][k] ----------------
__global__ void nj_kernel(const float2* __restrict__ qm,
                          const float2* __restrict__ gkm,
                          const int* __restrict__ g,
                          float2* __restrict__ njm) {
  int lj = blockIdx.y;
  int idx = blockIdx.x * 256 + threadIdx.x;
  int i = idx >> 7, c = idx & 127;
  int gc = g[c];
  const float2* q = qm + (size_t)lj * 16384;
  const float2* gk = gkm + (size_t)lj * 16384;
  float2 acc = make_float2(0.f, 0.f);
  for (int k = 0; k < 128; ++k) {
    float2 qa = q[k * 128 + i];
    float2 gb = gk[gc * 128 + k];
    acc.x += qa.x * gb.x - qa.y * gb.y;
    acc.y += qa.x * gb.y + qa.y * gb.x;
  }
  njm[(size_t)lj * 16384 + idx] = acc;
}

// ---------------- U_l = N_{l,0} @ N_{l,1} ----------------
__global__ void compose_kernel(const float2* __restrict__ njm,
                               float2* __restrict__ um) {
  int l = blockIdx.y;
  int idx = blockIdx.x * 256 + threadIdx.x;
  int i = idx >> 7, c = idx & 127;
  const float2* n0 = njm + (size_t)(l * 2 + 0) * 16384;
  const float2* n1 = njm + (size_t)(l * 2 + 1) * 16384;
  float2 acc = make_float2(0.f, 0.f);
  for (int k = 0; k < 128; ++k) {
    float2 a = n0[i * 128 + k];
    float2 b = n1[k * 128 + c];
    acc.x += a.x * b.x - a.y * b.y;
    acc.y += a.x * b.y + a.y * b.x;
  }
  um[(size_t)l * 16384 + idx] = acc;
}

// ---------------- Wqd_l = Re(U_l) @ dec_w_l ----------------
__global__ void wqd_kernel(const float2* __restrict__ um,
                           const float* __restrict__ decw,
                           float* __restrict__ wqd) {
  int l = blockIdx.y;
  int idx = blockIdx.x * 256 + threadIdx.x;
  int i = idx >> 7, c = idx & 127;
  const float2* u = um + (size_t)l * 16384;
  const float* dw = decw + (size_t)l * 16384;
  float acc = 0.f;
  for (int k = 0; k < 128; ++k) acc += u[i * 128 + k].x * dw[k * 128 + c];
  wqd[(size_t)l * 16384 + idx] = acc;
}

// ==================== MFMA edge MLP + segmented scatter ====================
// 64 sorted edges/block. GEMM1: A(64x288bf16) @ W1cs -> silu -> m1(bf16)
// GEMM2: m1 @ W2cs -> silu -> m2(f32, overlays A) -> segmented reduce -> atomics
__global__ __launch_bounds__(256) void edge_mfma_kernel(
    const ushort* __restrict__ hbf, const int* __restrict__ ei,
    const float* __restrict__ x, const float* __restrict__ ea,
    const int* __restrict__ elist,
    const ushort* __restrict__ w1cs, const float* __restrict__ b1,
    const ushort* __restrict__ w2cs, const float* __restrict__ b2,
    float* __restrict__ agg) {
  __shared__ ushort A[EPB * AS];       // 37,888 B ; m2 (f32 64x136=34,816B) overlays
  __shared__ ushort wbuf[4096];        // 8,192 B
  __shared__ ushort m1[EPB * MS];      // 17,408 B
  __shared__ int rows[EPB];
  float* m2 = (float*)A;

  const int tid = threadIdx.x;
  const int i0 = blockIdx.x * EPB;

  // ---- gather A ----
  {
    const int e = tid >> 2, j = tid & 3;   // 4 threads/edge, 32 bf16 cols each
    const int edge = elist[i0 + e];
    const int r = ei[edge], c = ei[N_EDGES + edge];
    if (j == 0) rows[e] = r;
    const uint4* hr = (const uint4*)(hbf + (size_t)r * HDIM + j * 32);
    const uint4* hc = (const uint4*)(hbf + (size_t)c * HDIM + j * 32);
    uint4* d1 = (uint4*)(A + e * AS + j * 32);
    uint4* d2 = (uint4*)(A + e * AS + 128 + j * 32);
    d1[0] = hr[0]; d1[1] = hr[1]; d1[2] = hr[2]; d1[3] = hr[3];
    d2[0] = hc[0]; d2[1] = hc[1]; d2[2] = hc[2]; d2[3] = hc[3];
    if (j == 3) {
      float dx = x[r * 3 + 0] - x[c * 3 + 0];
      float dy = x[r * 3 + 1] - x[c * 3 + 1];
      float dz = x[r * 3 + 2] - x[c * 3 + 2];
      ushort* dst = A + e * AS;
      dst[256] = f2bf(dx * dx + dy * dy + dz * dz);
      dst[257] = f2bf(ea[edge]);
#pragma unroll
      for (int z = 258; z < 288; ++z) dst[z] = 0;
    }
  }

  const int lane = tid & 63, wave = tid >> 6;
  const int m0 = wave * 16;
  const int lrow = lane & 15, lq = lane >> 4;

  // ---- GEMM1 ----
  f32x4 acc[8];
#pragma unroll
  for (int t = 0; t < 8; ++t) acc[t] = (f32x4){0.f, 0.f, 0.f, 0.f};
  for (int kt = 0; kt < 9; ++kt) {
    __syncthreads();
    {
      const uint4* src = (const uint4*)(w1cs + kt * 4096);
      uint4* dw = (uint4*)wbuf;
      dw[tid] = src[tid];
      dw[tid + 256] = src[tid + 256];
    }
    __syncthreads();
    short8b af = *(const short8b*)(A + (m0 + lrow) * AS + kt * 32 + lq * 8);
#pragma unroll
    for (int t = 0; t < 8; ++t) {
      short8b bfv = *(const short8b*)(wbuf + (t * 16 + lrow) * 32 + lq * 8);
      acc[t] = __builtin_amdgcn_mfma_f32_16x16x32_bf16(af, bfv, acc[t], 0, 0, 0);
    }
  }
  // silu -> m1 (bf16). C/D layout: col=lane&15, row=quad*4+reg.
#pragma unroll
  for (int t = 0; t < 8; ++t) {
    float bb = b1[t * 16 + lrow];
#pragma unroll
    for (int r = 0; r < 4; ++r)
      m1[(m0 + lq * 4 + r) * MS + t * 16 + lrow] = f2bf(silu_f(acc[t][r] + bb));
  }

  // ---- GEMM2 ----
  f32x4 acc2[8];
#pragma unroll
  for (int t = 0; t < 8; ++t) acc2[t] = (f32x4){0.f, 0.f, 0.f, 0.f};
  for (int kt = 0; kt < 4; ++kt) {
    __syncthreads();
    {
      const uint4* src = (const uint4*)(w2cs + kt * 4096);
      uint4* dw = (uint4*)wbuf;
      dw[tid] = src[tid];
      dw[tid + 256] = src[tid + 256];
    }
    __syncthreads();
    short8b af = *(const short8b*)(m1 + (m0 + lrow) * MS + kt * 32 + lq * 8);
#pragma unroll
    for (int t = 0; t < 8; ++t) {
      short8b bfv = *(const short8b*)(wbuf + (t * 16 + lrow) * 32 + lq * 8);
      acc2[t] = __builtin_amdgcn_mfma_f32_16x16x32_bf16(af, bfv, acc2[t], 0, 0, 0);
    }
  }
  __syncthreads();   // A-tile reads long done; safe to overlay m2
#pragma unroll
  for (int t = 0; t < 8; ++t) {
    float bb = b2[t * 16 + lrow];
#pragma unroll
    for (int r = 0; r < 4; ++r)
      m2[(m0 + lq * 4 + r) * MS + t * 16 + lrow] = silu_f(acc2[t][r] + bb);
  }
  __syncthreads();

  // ---- segmented reduce over sorted rows + atomics ----
  const int e2 = tid & 63, cg = tid >> 6, cb = cg * 32;
  const int r_e = rows[e2];
  const bool leader = (e2 == 0) || (rows[e2 - 1] != r_e);
  if (leader) {
    float sum[32];
#pragma unroll
    for (int j = 0; j < 32; ++j) sum[j] = m2[e2 * MS + cb + j];
    int f = e2 + 1;
    while (f < EPB && rows[f] == r_e) {
#pragma unroll
      for (int j = 0; j < 32; ++j) sum[j] += m2[f * MS + cb + j];
      ++f;
    }
    float* ap = agg + (size_t)r_e * HDIM + cb;
#pragma unroll
    for (int j = 0; j < 32; ++j) atomicAdd(&ap[j], sum[j]);
  }
}

// ==================== MFMA node update ====================
// h += rownorm([h | agg/100] @ enc) @ Wqd + dec_b ; also writes hbf
__global__ __launch_bounds__(256) void node_mfma_kernel(
    float* __restrict__ out_h, const float* __restrict__ agg,
    const ushort* __restrict__ enccs, const float* __restrict__ encb,
    const ushort* __restrict__ wqdcs, const float* __restrict__ decb,
    ushort* __restrict__ hbf) {
  __shared__ ushort A[EPB * NAS];      // 33,792 B
  __shared__ ushort wbuf[4096];
  __shared__ ushort m1[EPB * MS];
  const int tid = threadIdx.x;
  const int n0 = blockIdx.x * EPB;

  // ---- build A = [h | agg*0.01] in bf16 ----
  {
    const int e = tid >> 2, j = tid & 3;   // 4 threads/node, 64 cols each
    const int node = n0 + e;
    const float* src = (j < 2) ? (out_h + (size_t)node * HDIM + j * 64)
                               : (agg + (size_t)node * HDIM + (j - 2) * 64);
    const float sc = (j < 2) ? 1.0f : 0.01f;
    ushort* dst = A + e * NAS + j * 64 + ((j < 2) ? 0 : 0);
    if (j >= 2) dst = A + e * NAS + 128 + (j - 2) * 64;
    const float4* s4 = (const float4*)src;
#pragma unroll
    for (int i = 0; i < 16; ++i) {
      float4 v = s4[i];
      ushort4 o;
      o.x = f2bf(v.x * sc); o.y = f2bf(v.y * sc);
      o.z = f2bf(v.z * sc); o.w = f2bf(v.w * sc);
      ((ushort4*)dst)[i] = o;
    }
  }

  const int lane = tid & 63, wave = tid >> 6;
  const int m0 = wave * 16;
  const int lrow = lane & 15, lq = lane >> 4;

  // ---- GEMM1: q = A @ enc ----
  f32x4 acc[8];
#pragma unroll
  for (int t = 0; t < 8; ++t) acc[t] = (f32x4){0.f, 0.f, 0.f, 0.f};
  for (int kt = 0; kt < 8; ++kt) {
    __syncthreads();
    {
      const uint4* src = (const uint4*)(enccs + kt * 4096);
      uint4* dw = (uint4*)wbuf;
      dw[tid] = src[tid];
      dw[tid + 256] = src[tid + 256];
    }
    __syncthreads();
    short8b af = *(const short8b*)(A + (m0 + lrow) * NAS + kt * 32 + lq * 8);
#pragma unroll
    for (int t = 0; t < 8; ++t) {
      short8b bfv = *(const short8b*)(wbuf + (t * 16 + lrow) * 32 + lq * 8);
      acc[t] = __builtin_amdgcn_mfma_f32_16x16x32_bf16(af, bfv, acc[t], 0, 0, 0);
    }
  }
  // bias + row-norm (across 128 cols = 8 tiles x 16 lanes)
#pragma unroll
  for (int t = 0; t < 8; ++t) {
    float bb = encb[t * 16 + lrow];
#pragma unroll
    for (int r = 0; r < 4; ++r) acc[t][r] += bb;
  }
  float ss[4] = {0.f, 0.f, 0.f, 0.f};
#pragma unroll
  for (int t = 0; t < 8; ++t)
#pragma unroll
    for (int r = 0; r < 4; ++r) ss[r] += acc[t][r] * acc[t][r];
#pragma unroll
  for (int m = 1; m < 16; m <<= 1) {
#pragma unroll
    for (int r = 0; r < 4; ++r) ss[r] += __shfl_xor(ss[r], m, 64);
  }
  float inv[4];
#pragma unroll
  for (int r = 0; r < 4; ++r) inv[r] = 1.0f / sqrtf(ss[r] + 1e-12f);
#pragma unroll
  for (int t = 0; t < 8; ++t)
#pragma unroll
    for (int r = 0; r < 4; ++r)
      m1[(m0 + lq * 4 + r) * MS + t * 16 + lrow] = f2bf(acc[t][r] * inv[r]);

  // ---- GEMM2: dec = m1 @ Wqd ----
  f32x4 acc2[8];
#pragma unroll
  for (int t = 0; t < 8; ++t) acc2[t] = (f32x4){0.f, 0.f, 0.f, 0.f};
  for (int kt = 0; kt < 4; ++kt) {
    __syncthreads();
    {
      const uint4* src = (const uint4*)(wqdcs + kt * 4096);
      uint4* dw = (uint4*)wbuf;
      dw[tid] = src[tid];
      dw[tid + 256] = src[tid + 256];
    }
    __syncthreads();
    short8b af = *(const short8b*)(m1 + (m0 + lrow) * MS + kt * 32 + lq * 8);
#pragma unroll
    for (int t = 0; t < 8; ++t) {
      short8b bfv = *(const short8b*)(wbuf + (t * 16 + lrow) * 32 + lq * 8);
      acc2[t] = __builtin_amdgcn_mfma_f32_16x16x32_bf16(af, bfv, acc2[t], 0, 0, 0);
    }
  }
  // epilogue: h_new = h_old + dec + dec_b ; write fp32 + bf16
#pragma unroll
  for (int t = 0; t < 8; ++t) {
    const int n = t * 16 + lrow;
    float bb = decb[n];
#pragma unroll
    for (int r = 0; r < 4; ++r) {
      const int node = n0 + m0 + lq * 4 + r;
      if (node < N_NODES) {
        size_t off = (size_t)node * HDIM + n;
        float hn = out_h[off] + acc2[t][r] + bb;
        out_h[off] = hn;
        hbf[off] = f2bf(hn);
      }
    }
  }
}

// ==================== MFMA coordinate head ====================
__global__ __launch_bounds__(256) void coord_mfma_kernel(
    const ushort* __restrict__ hbf, const int* __restrict__ ei,
    const float* __restrict__ x, const float* __restrict__ ea,
    const int* __restrict__ elist,
    const ushort* __restrict__ w1cs, const float* __restrict__ b1,
    const ushort* __restrict__ w2cs, const float* __restrict__ b2,
    const float* __restrict__ w3, float* __restrict__ xout) {
  __shared__ ushort A[EPB * AS];
  __shared__ ushort wbuf[4096];
  __shared__ ushort m1[EPB * MS];
  __shared__ int rows[EPB];
  __shared__ int colsA[EPB];
  __shared__ float tv[EPB];

  const int tid = threadIdx.x;
  const int i0 = blockIdx.x * EPB;

  {
    const int e = tid >> 2, j = tid & 3;
    const int edge = elist[i0 + e];
    const int r = ei[edge], c = ei[N_EDGES + edge];
    if (j == 0) { rows[e] = r; colsA[e] = c; }
    const uint4* hr = (const uint4*)(hbf + (size_t)r * HDIM + j * 32);
    const uint4* hc = (const uint4*)(hbf + (size_t)c * HDIM + j * 32);
    uint4* d1 = (uint4*)(A + e * AS + j * 32);
    uint4* d2 = (uint4*)(A + e * AS + 128 + j * 32);
    d1[0] = hr[0]; d1[1] = hr[1]; d1[2] = hr[2]; d1[3] = hr[3];
    d2[0] = hc[0]; d2[1] = hc[1]; d2[2] = hc[2]; d2[3] = hc[3];
    if (j == 3) {
      float dx = x[r * 3 + 0] - x[c * 3 + 0];
      float dy = x[r * 3 + 1] - x[c * 3 + 1];
      float dz = x[r * 3 + 2] - x[c * 3 + 2];
      ushort* dst = A + e * AS;
      dst[256] = f2bf(dx * dx + dy * dy + dz * dz);
      dst[257] = f2bf(ea[edge]);
#pragma unroll
      for (int z = 258; z < 288; ++z) dst[z] = 0;
    }
  }

  const int lane = tid & 63, wave = tid >> 6;
  const int m0 = wave * 16;
  const int lrow = lane & 15, lq = lane >> 4;

  f32x4 acc[8];
#pragma unroll
  for (int t = 0; t < 8; ++t) acc[t] = (f32x4){0.f, 0.f, 0.f, 0.f};
  for (int kt = 0; kt < 9; ++kt) {
    __syncthreads();
    {
      const uint4* src = (const uint4*)(w1cs + kt * 4096);
      uint4* dw = (uint4*)wbuf;
      dw[tid] = src[tid];
      dw[tid + 256] = src[tid + 256];
    }
    __syncthreads();
    short8b af = *(const short8b*)(A + (m0 + lrow) * AS + kt * 32 + lq * 8);
#pragma unroll
    for (int t = 0; t < 8; ++t) {
      short8b bfv = *(const short8b*)(wbuf + (t * 16 + lrow) * 32 + lq * 8);
      acc[t] = __builtin_amdgcn_mfma_f32_16x16x32_bf16(af, bfv, acc[t], 0, 0, 0);
    }
  }
#pragma unroll
  for (int t = 0; t < 8; ++t) {
    float bb = b1[t * 16 + lrow];
#pragma unroll
    for (int r = 0; r < 4; ++r)
      m1[(m0 + lq * 4 + r) * MS + t * 16 + lrow] = f2bf(silu_f(acc[t][r] + bb));
  }

  f32x4 acc2[8];
#pragma unroll
  for (int t = 0; t < 8; ++t) acc2[t] = (f32x4){0.f, 0.f, 0.f, 0.f};
  for (int kt = 0; kt < 4; ++kt) {
    __syncthreads();
    {
      const uint4* src = (const uint4*)(w2cs + kt * 4096);
      uint4* dw = (uint4*)wbuf;
      dw[tid] = src[tid];
      dw[tid + 256] = src[tid + 256];
    }
    __syncthreads();
    short8b af = *(const short8b*)(m1 + (m0 + lrow) * MS + kt * 32 + lq * 8);
#pragma unroll
    for (int t = 0; t < 8; ++t) {
      short8b bfv = *(const short8b*)(wbuf + (t * 16 + lrow) * 32 + lq * 8);
      acc2[t] = __builtin_amdgcn_mfma_f32_16x16x32_bf16(af, bfv, acc2[t], 0, 0, 0);
    }
  }
  // t_e = sum_n silu(C2[e][n]+b2[n]) * w3[n]
  float p[4] = {0.f, 0.f, 0.f, 0.f};
#pragma unroll
  for (int t = 0; t < 8; ++t) {
    const int n = t * 16 + lrow;
    float bb = b2[n];
    float wv = w3[n];
#pragma unroll
    for (int r = 0; r < 4; ++r) p[r] += silu_f(acc2[t][r] + bb) * wv;
  }
#pragma unroll
  for (int m = 1; m < 16; m <<= 1) {
#pragma unroll
    for (int r = 0; r < 4; ++r) p[r] += __shfl_xor(p[r], m, 64);
  }
  if (lrow == 0) {
#pragma unroll
    for (int r = 0; r < 4; ++r) tv[m0 + lq * 4 + r] = p[r] * 0.01f;
  }
  __syncthreads();
  if (tid < EPB) {
    const int e = tid;
    const int r_e = rows[e];
    const bool leader = (e == 0) || (rows[e - 1] != r_e);
    if (leader) {
      float sx = 0.f, sy = 0.f, sz = 0.f;
      int f = e;
      do {
        const int c = colsA[f];
        float dx = x[r_e * 3 + 0] - x[c * 3 + 0];
        float dy = x[r_e * 3 + 1] - x[c * 3 + 1];
        float dz = x[r_e * 3 + 2] - x[c * 3 + 2];
        float radial = dx * dx + dy * dy + dz * dz;
        float s = 1.0f / (sqrtf(radial + 1e-8f) + 1.0f);
        float t = tv[f];
        sx += dx * s * t; sy += dy * s * t; sz += dz * s * t;
        ++f;
      } while (f < EPB && rows[f] == r_e);
      atomicAdd(&xout[r_e * 3 + 0], sx);
      atomicAdd(&xout[r_e * 3 + 1], sy);
      atomicAdd(&xout[r_e * 3 + 2], sz);
    }
  }
}

extern "C" void kernel_launch(void* const* d_in, const int* in_sizes, int n_in,
                              void* d_out, int out_size, void* d_ws, size_t ws_size,
                              hipStream_t stream) {
  const float* h     = (const float*)d_in[0];
  const float* x     = (const float*)d_in[1];
  const int*   ei    = (const int*)d_in[2];
  const float* ea    = (const float*)d_in[3];
  const float* e_w1  = (const float*)d_in[4];
  const float* e_b1  = (const float*)d_in[5];
  const float* e_w2  = (const float*)d_in[6];
  const float* e_b2  = (const float*)d_in[7];
  const float* enc_w = (const float*)d_in[8];
  const float* enc_b = (const float*)d_in[9];
  const float* coeffs= (const float*)d_in[10];
  const float* A_re  = (const float*)d_in[11];
  const float* A_im  = (const float*)d_in[12];
  const float* dec_w = (const float*)d_in[13];
  const float* dec_b = (const float*)d_in[14];
  const float* c_w1  = (const float*)d_in[15];
  const float* c_b1  = (const float*)d_in[16];
  const float* c_w2  = (const float*)d_in[17];
  const float* c_b2  = (const float*)d_in[18];
  const float* c_w3  = (const float*)d_in[19];

  float* out = (float*)d_out;
  float* ws  = (float*)d_ws;

  // workspace layout (float offsets) — ~28.6 MB
  float*  agg    = ws;                          // 3,840,000
  float2* aug    = (float2*)(ws + 3840000);     // 262,144 f
  float2* qm     = (float2*)(ws + 4102144);     // 131,072 f
  float2* gkm    = (float2*)(ws + 4233216);     // 131,072 f
  float2* njm    = (float2*)(ws + 4364288);     // 131,072 f
  float2* um     = (float2*)(ws + 4495360);     //  65,536 f
  float*  wqd    = ws + 4560896;                //  32,768 f
  int*    perm   = (int*)(ws + 4593664);        //     128
  int*    cursor = (int*)(ws + 4593792);        //  30,000
  int*    elist  = (int*)(ws + 4623792);        // 480,000
  ushort* hbf    = (ushort*)(ws + 5103792);     // 1,920,000 f
  ushort* w1cs   = (ushort*)(ws + 7023792);     // 2*9*4096 us = 36,864 f
  ushort* w2cs   = (ushort*)(ws + 7060656);     // 2*4*4096 us = 16,384 f
  ushort* cw1cs  = (ushort*)(ws + 7077040);     // 9*4096 us   = 18,432 f
  ushort* cw2cs  = (ushort*)(ws + 7095472);     // 4*4096 us   =  8,192 f
  ushort* enccs  = (ushort*)(ws + 7103664);     // 2*8*4096 us = 32,768 f
  ushort* wqdcs  = (ushort*)(ws + 7136432);     // 2*4*4096 us = 16,384 f

  init_out_kernel<<<15000, 256, 0, stream>>>(h, x, out);

  // counting sort of edges by destination row
  hipMemsetAsync(cursor, 0, N_NODES * sizeof(int), stream);
  count_kernel<<<1875, 256, 0, stream>>>(ei, cursor);
  scan_kernel<<<1, 1024, 0, stream>>>(cursor);
  fill_kernel<<<1875, 256, 0, stream>>>(ei, cursor, elist);

  // quantum-operator precompute (tiny)
  perm_kernel<<<1, 128, 0, stream>>>(perm);
  build_aug_kernel<<<dim3(128, 4), 256, 0, stream>>>(A_re, A_im, aug);
  gj_kernel<<<4, 1024, 0, stream>>>(aug);
  qmat_kernel<<<dim3(64, 4), 256, 0, stream>>>(A_re, A_im, aug, qm);
  gk_kernel<<<dim3(64, 4), 256, 0, stream>>>(coeffs, gkm);
  nj_kernel<<<dim3(64, 4), 256, 0, stream>>>(qm, gkm, perm, njm);
  compose_kernel<<<dim3(64, 2), 256, 0, stream>>>(njm, um);
  wqd_kernel<<<dim3(64, 2), 256, 0, stream>>>(um, dec_w, wqd);

  // weight conversions to chunked bf16 [kt][n][kk]
  for (int l = 0; l < 2; ++l) {
    convert_w_kernel<<<144, 256, 0, stream>>>(e_w1 + (size_t)l * 258 * HDIM,
                                              w1cs + (size_t)l * 9 * 4096, 258, 9);
    convert_w_kernel<<<64, 256, 0, stream>>>(e_w2 + (size_t)l * HDIM * HDIM,
                                             w2cs + (size_t)l * 4 * 4096, 128, 4);
    convert_w_kernel<<<128, 256, 0, stream>>>(enc_w + (size_t)l * 256 * HDIM,
                                              enccs + (size_t)l * 8 * 4096, 256, 8);
    convert_w_kernel<<<64, 256, 0, stream>>>(wqd + (size_t)l * HDIM * HDIM,
                                             wqdcs + (size_t)l * 4 * 4096, 128, 4);
  }
  convert_w_kernel<<<144, 256, 0, stream>>>(c_w1, cw1cs, 258, 9);
  convert_w_kernel<<<64, 256, 0, stream>>>(c_w2, cw2cs, 128, 4);

  // initial bf16 h
  h_to_bf_kernel<<<3750, 256, 0, stream>>>(out, hbf);

  // two message-passing layers
  for (int l = 0; l < 2; ++l) {
    hipMemsetAsync(agg, 0, (size_t)N_NODES * HDIM * sizeof(float), stream);
    edge_mfma_kernel<<<N_EDGES / EPB, 256, 0, stream>>>(
        hbf, ei, x, ea, elist,
        w1cs + (size_t)l * 9 * 4096, e_b1 + l * HDIM,
        w2cs + (size_t)l * 4 * 4096, e_b2 + l * HDIM, agg);
    node_mfma_kernel<<<(N_NODES + EPB - 1) / EPB, 256, 0, stream>>>(
        out, agg,
        enccs + (size_t)l * 8 * 4096, enc_b + l * HDIM,
        wqdcs + (size_t)l * 4 * 4096, dec_b + l * HDIM, hbf);
  }

  // coordinate head
  coord_mfma_kernel<<<N_EDGES / EPB, 256, 0, stream>>>(
      hbf, ei, x, ea, elist, cw1cs, c_b1, cw2cs, c_b2, c_w3,
      out + (size_t)N_NODES * HDIM);
}

// Round 4
// 1900.630 us; speedup vs baseline: 6.2483x; 1.2945x over previous
//
#include <hip/hip_runtime.h>
#include <math.h>

#define N_NODES 30000
#define N_EDGES 480000
#define HDIM 128
#define EPB 64        // edges (or nodes) per MFMA block
#define AS 296        // A-tile row stride (bf16)
#define NAS 264       // node A-tile row stride (bf16)
#define MS 136        // m1 row stride (bf16) / m2 stride (f32)

typedef __attribute__((ext_vector_type(8))) short short8b;
typedef __attribute__((ext_vector_type(4))) float f32x4;

__device__ __forceinline__ float silu_f(float v) {
  return v / (1.0f + __expf(-v));
}

__device__ __forceinline__ unsigned short f2bf(float f) {
  unsigned int u = __float_as_uint(f);
  unsigned int r = u + 0x7fffu + ((u >> 16) & 1u);
  return (unsigned short)(r >> 16);
}

__device__ __forceinline__ float2 cmul(float2 a, float2 b) {
  return make_float2(a.x * b.x - a.y * b.y, a.x * b.y + a.y * b.x);
}

// ---------------- output init: out = [h | x] ----------------
__global__ void init_out_kernel(const float* __restrict__ h,
                                const float* __restrict__ x,
                                float* __restrict__ out) {
  int idx = blockIdx.x * 256 + threadIdx.x;
  out[idx] = h[idx];
  if (idx < N_NODES * 3) out[N_NODES * HDIM + idx] = x[idx];
}

// ---------------- h (fp32) -> hbf (bf16) ----------------
__global__ void h_to_bf_kernel(const float* __restrict__ h,
                               ushort* __restrict__ hbf) {
  int idx = blockIdx.x * 256 + threadIdx.x;
  float4 v = ((const float4*)h)[idx];
  ushort4 o;
  o.x = f2bf(v.x); o.y = f2bf(v.y); o.z = f2bf(v.z); o.w = f2bf(v.w);
  ((ushort4*)hbf)[idx] = o;
}

// ---------------- weight convert: W[K][128] fp32 -> [KT][128][32] bf16 ----
__global__ void convert_w_kernel(const float* __restrict__ W,
                                 ushort* __restrict__ dst, int Kreal, int KT) {
  int idx = blockIdx.x * 256 + threadIdx.x;
  if (idx >= KT * 4096) return;
  int kt = idx >> 12, rem = idx & 4095, n = rem >> 5, kk = rem & 31;
  int k = kt * 32 + kk;
  float v = (k < Kreal) ? W[(size_t)k * HDIM + n] : 0.0f;
  dst[idx] = f2bf(v);
}

// ---------------- counting sort of edges by destination row ----------------
__global__ void count_kernel(const int* __restrict__ ei, int* __restrict__ cursor) {
  int e = blockIdx.x * 256 + threadIdx.x;
  atomicAdd(&cursor[ei[e]], 1);
}

__global__ __launch_bounds__(1024) void scan_kernel(int* __restrict__ cursor) {
  __shared__ int sums[1024];
  const int tid = threadIdx.x;
  const int base = tid * 30;
  int local[30];
  int s = 0;
#pragma unroll
  for (int j = 0; j < 30; ++j) {
    int idx = base + j;
    int d = (idx < N_NODES) ? cursor[idx] : 0;
    local[j] = s;
    s += d;
  }
  sums[tid] = s;
  __syncthreads();
  for (int off = 1; off < 1024; off <<= 1) {
    int add = (tid >= off) ? sums[tid - off] : 0;
    __syncthreads();
    sums[tid] += add;
    __syncthreads();
  }
  int excl = (tid == 0) ? 0 : sums[tid - 1];
#pragma unroll
  for (int j = 0; j < 30; ++j) {
    int idx = base + j;
    if (idx < N_NODES) cursor[idx] = excl + local[j];
  }
}

__global__ void fill_kernel(const int* __restrict__ ei, int* __restrict__ cursor,
                            int* __restrict__ elist) {
  int e = blockIdx.x * 256 + threadIdx.x;
  int r = ei[e];
  int pos = atomicAdd(&cursor[r], 1);
  elist[pos] = e;
}

// ---------------- CNOT ring permutation ----------------
__global__ void perm_kernel(int* __restrict__ g) {
  int i = threadIdx.x;
  int v = i;
  const int cs[7] = {6, 5, 4, 3, 2, 1, 0};
  const int ts[7] = {0, 6, 5, 4, 3, 2, 1};
#pragma unroll
  for (int p = 0; p < 7; ++p) {
    int cb = (v >> (6 - cs[p])) & 1;
    v = v ^ (cb << (6 - ts[p]));
  }
  g[i] = v;
}

// ============ register-resident Gauss-Jordan, fused with build_aug ========
// One block per (layer,j) matrix. 1024 threads: thread (c=tid&255, rg=tid>>8)
// holds rows rg*32..rg*32+31 of column c in registers. Pivot rows stay
// UNSCALED in registers; per-row scale sigma_r (=ipiv at iteration r) is
// folded lazily at the end (stored-space update is sigma-free; verified).
// Active-column window [p, p+128] halves the VALU work (outside-window pivot
// row entries are exactly 0/identity). Writes Binv (cols 128..255) to binv.
__global__ __launch_bounds__(1024) void gj_reg_kernel(
    const float* __restrict__ Are, const float* __restrict__ Aim,
    float2* __restrict__ binv) {
  const int lj = blockIdx.x;
  const float* are = Are + (size_t)lj * 16384;
  const float* aim = Aim + (size_t)lj * 16384;
  float2* bout = binv + (size_t)lj * 32768;

  __shared__ float2 fbuf[128];    // column p (unscaled)
  __shared__ float2 rowbuf[256];  // pivot row p (unscaled)
  __shared__ float2 sig[128];     // per-row lazy scale

  const int tid = threadIdx.x;
  const int c = tid & 255, rg = tid >> 8;
  const int r0 = rg * 32;

  float2 reg[32];
  // ---- init augmented [A_h + iI | I] ----
  if (c < 128) {
#pragma unroll
    for (int rr = 0; rr < 32; ++rr) {
      int r = r0 + rr;
      float re = are[r * 128 + c] + are[c * 128 + r];
      float im = aim[r * 128 + c] - aim[c * 128 + r];
      if (r == c) im += 1.0f;
      reg[rr] = make_float2(re, im);
    }
  } else {
    int cc = c - 128;
#pragma unroll
    for (int rr = 0; rr < 32; ++rr)
      reg[rr] = make_float2((r0 + rr == cc) ? 1.0f : 0.0f, 0.0f);
  }
  __syncthreads();

  for (int p = 0; p < 128; ++p) {
    // column-p threads dump their 32 rows (static indices)
    if (c == p) {
#pragma unroll
      for (int rr = 0; rr < 32; ++rr) fbuf[r0 + rr] = reg[rr];
    }
    __syncthreads();
    float2 piv = fbuf[p];
    float d = piv.x * piv.x + piv.y * piv.y;
    float2 ip = make_float2(piv.x / d, -piv.y / d);
    if (tid == 0) sig[p] = ip;
    // pivot-row threads publish their (unscaled) element via 32-way select
    if (rg == (p >> 5)) {
      int pl = p & 31;
      float2 s = reg[0];
#pragma unroll
      for (int k = 1; k < 32; ++k)
        if (pl == k) s = reg[k];
      rowbuf[c] = s;
    }
    __syncthreads();
    // update (window: only columns [p, p+128] can change)
    if (c >= p && c <= p + 128) {
      float2 pr = cmul(ip, rowbuf[c]);
      int prr = p - r0;   // wave-uniform
#pragma unroll
      for (int rr = 0; rr < 32; ++rr) {
        if (rr != prr) {
          float2 f = fbuf[r0 + rr];
          reg[rr].x -= f.x * pr.x - f.y * pr.y;
          reg[rr].y -= f.x * pr.y + f.y * pr.x;
        }
      }
    }
    __syncthreads();
  }

  // ---- write sigma-scaled inverse half ----
  if (c >= 128) {
#pragma unroll
    for (int rr = 0; rr < 32; ++rr) {
      int r = r0 + rr;
      bout[r * 256 + c] = cmul(sig[r], reg[rr]);
    }
  }
}

// ---------------- q = (A_h - iI) * Binv ----------------
__global__ void qmat_kernel(const float* __restrict__ Are,
                            const float* __restrict__ Aim,
                            const float2* __restrict__ augg,
                            float2* __restrict__ qm) {
  int lj = blockIdx.y;
  int idx = blockIdx.x * 256 + threadIdx.x;
  int r = idx >> 7, c = idx & 127;
  const float* are = Are + (size_t)lj * 16384;
  const float* aim = Aim + (size_t)lj * 16384;
  const float2* binv = augg + (size_t)lj * 32768;
  float2 acc = make_float2(0.f, 0.f);
  for (int k = 0; k < 128; ++k) {
    float re = are[r * 128 + k] + are[k * 128 + r];
    float im = aim[r * 128 + k] - aim[k * 128 + r];
    if (k == r) im -= 1.0f;
    float2 b = binv[k * 256 + 128 + c];
    acc.x += re * b.x - im * b.y;
    acc.y += re * b.y + im * b.x;
  }
  qm[(size_t)lj * 16384 + idx] = acc;
}

// ---------------- Gk = (RY*RX)^(kron 7) ----------------
__global__ void gk_kernel(const float* __restrict__ coeffs,
                          float2* __restrict__ gkm) {
  int lj = blockIdx.y;
  float a = coeffs[lj * 2 + 0], b = coeffs[lj * 2 + 1];
  float ca = cosf(0.5f * a), sa = sinf(0.5f * a);
  float cb = cosf(0.5f * b), sb = sinf(0.5f * b);
  float2 G[2][2];
  G[0][0] = make_float2(cb * ca, sb * sa);
  G[0][1] = make_float2(-sb * ca, -cb * sa);
  G[1][0] = make_float2(sb * ca, -cb * sa);
  G[1][1] = make_float2(cb * ca, -sb * sa);
  int idx = blockIdx.x * 256 + threadIdx.x;
  int r = idx >> 7, c = idx & 127;
  float2 acc = make_float2(1.f, 0.f);
#pragma unroll
  for (int bit = 6; bit >= 0; --bit) {
    float2 g = G[(r >> bit) & 1][(c >> bit) & 1];
    acc = make_float2(acc.x * g.x - acc.y * g.y, acc.x * g.y + acc.y * g.x);
  }
  gkm[(size_t)lj * 16384 + idx] = acc;
}

// ---------------- N_j[i][c] = sum_k q[k][i] * Gk[g[c]][k] ----------------
__global__ void nj_kernel(const float2* __restrict__ qm,
                          const float2* __restrict__ gkm,
                          const int* __restrict__ g,
                          float2* __restrict__ njm) {
  int lj = blockIdx.y;
  int idx = blockIdx.x * 256 + threadIdx.x;
  int i = idx >> 7, c = idx & 127;
  int gc = g[c];
  const float2* q = qm + (size_t)lj * 16384;
  const float2* gk = gkm + (size_t)lj * 16384;
  float2 acc = make_float2(0.f, 0.f);
  for (int k = 0; k < 128; ++k) {
    float2 qa = q[k * 128 + i];
    float2 gb = gk[gc * 128 + k];
    acc.x += qa.x * gb.x - qa.y * gb.y;
    acc.y += qa.x * gb.y + qa.y * gb.x;
  }
  njm[(size_t)lj * 16384 + idx] = acc;
}

// ---------------- U_l = N_{l,0} @ N_{l,1} ----------------
__global__ void compose_kernel(const float2* __restrict__ njm,
                               float2* __restrict__ um) {
  int l = blockIdx.y;
  int idx = blockIdx.x * 256 + threadIdx.x;
  int i = idx >> 7, c = idx & 127;
  const float2* n0 = njm + (size_t)(l * 2 + 0) * 16384;
  const float2* n1 = njm + (size_t)(l * 2 + 1) * 16384;
  float2 acc = make_float2(0.f, 0.f);
  for (int k = 0; k < 128; ++k) {
    float2 a = n0[i * 128 + k];
    float2 b = n1[k * 128 + c];
    acc.x += a.x * b.x - a.y * b.y;
    acc.y += a.x * b.y + a.y * b.x;
  }
  um[(size_t)l * 16384 + idx] = acc;
}

// ---------------- Wqd_l = Re(U_l) @ dec_w_l ----------------
__global__ void wqd_kernel(const float2* __restrict__ um,
                           const float* __restrict__ decw,
                           float* __restrict__ wqd) {
  int l = blockIdx.y;
  int idx = blockIdx.x * 256 + threadIdx.x;
  int i = idx >> 7, c = idx & 127;
  const float2* u = um + (size_t)l * 16384;
  const float* dw = decw + (size_t)l * 16384;
  float acc = 0.f;
  for (int k = 0; k < 128; ++k) acc += u[i * 128 + k].x * dw[k * 128 + c];
  wqd[(size_t)l * 16384 + idx] = acc;
}

// ==================== MFMA edge MLP + segmented scatter ====================
__global__ __launch_bounds__(256) void edge_mfma_kernel(
    const ushort* __restrict__ hbf, const int* __restrict__ ei,
    const float* __restrict__ x, const float* __restrict__ ea,
    const int* __restrict__ elist,
    const ushort* __restrict__ w1cs, const float* __restrict__ b1,
    const ushort* __restrict__ w2cs, const float* __restrict__ b2,
    float* __restrict__ agg) {
  __shared__ ushort A[EPB * AS];
  __shared__ ushort wbuf[4096];
  __shared__ ushort m1[EPB * MS];
  __shared__ int rows[EPB];
  float* m2 = (float*)A;

  const int tid = threadIdx.x;
  const int i0 = blockIdx.x * EPB;

  {
    const int e = tid >> 2, j = tid & 3;
    const int edge = elist[i0 + e];
    const int r = ei[edge], c = ei[N_EDGES + edge];
    if (j == 0) rows[e] = r;
    const uint4* hr = (const uint4*)(hbf + (size_t)r * HDIM + j * 32);
    const uint4* hc = (const uint4*)(hbf + (size_t)c * HDIM + j * 32);
    uint4* d1 = (uint4*)(A + e * AS + j * 32);
    uint4* d2 = (uint4*)(A + e * AS + 128 + j * 32);
    d1[0] = hr[0]; d1[1] = hr[1]; d1[2] = hr[2]; d1[3] = hr[3];
    d2[0] = hc[0]; d2[1] = hc[1]; d2[2] = hc[2]; d2[3] = hc[3];
    if (j == 3) {
      float dx = x[r * 3 + 0] - x[c * 3 + 0];
      float dy = x[r * 3 + 1] - x[c * 3 + 1];
      float dz = x[r * 3 + 2] - x[c * 3 + 2];
      ushort* dst = A + e * AS;
      dst[256] = f2bf(dx * dx + dy * dy + dz * dz);
      dst[257] = f2bf(ea[edge]);
#pragma unroll
      for (int z = 258; z < 288; ++z) dst[z] = 0;
    }
  }

  const int lane = tid & 63, wave = tid >> 6;
  const int m0 = wave * 16;
  const int lrow = lane & 15, lq = lane >> 4;

  f32x4 acc[8];
#pragma unroll
  for (int t = 0; t < 8; ++t) acc[t] = (f32x4){0.f, 0.f, 0.f, 0.f};
  for (int kt = 0; kt < 9; ++kt) {
    __syncthreads();
    {
      const uint4* src = (const uint4*)(w1cs + kt * 4096);
      uint4* dw = (uint4*)wbuf;
      dw[tid] = src[tid];
      dw[tid + 256] = src[tid + 256];
    }
    __syncthreads();
    short8b af = *(const short8b*)(A + (m0 + lrow) * AS + kt * 32 + lq * 8);
#pragma unroll
    for (int t = 0; t < 8; ++t) {
      short8b bfv = *(const short8b*)(wbuf + (t * 16 + lrow) * 32 + lq * 8);
      acc[t] = __builtin_amdgcn_mfma_f32_16x16x32_bf16(af, bfv, acc[t], 0, 0, 0);
    }
  }
#pragma unroll
  for (int t = 0; t < 8; ++t) {
    float bb = b1[t * 16 + lrow];
#pragma unroll
    for (int r = 0; r < 4; ++r)
      m1[(m0 + lq * 4 + r) * MS + t * 16 + lrow] = f2bf(silu_f(acc[t][r] + bb));
  }

  f32x4 acc2[8];
#pragma unroll
  for (int t = 0; t < 8; ++t) acc2[t] = (f32x4){0.f, 0.f, 0.f, 0.f};
  for (int kt = 0; kt < 4; ++kt) {
    __syncthreads();
    {
      const uint4* src = (const uint4*)(w2cs + kt * 4096);
      uint4* dw = (uint4*)wbuf;
      dw[tid] = src[tid];
      dw[tid + 256] = src[tid + 256];
    }
    __syncthreads();
    short8b af = *(const short8b*)(m1 + (m0 + lrow) * MS + kt * 32 + lq * 8);
#pragma unroll
    for (int t = 0; t < 8; ++t) {
      short8b bfv = *(const short8b*)(wbuf + (t * 16 + lrow) * 32 + lq * 8);
      acc2[t] = __builtin_amdgcn_mfma_f32_16x16x32_bf16(af, bfv, acc2[t], 0, 0, 0);
    }
  }
  __syncthreads();
#pragma unroll
  for (int t = 0; t < 8; ++t) {
    float bb = b2[t * 16 + lrow];
#pragma unroll
    for (int r = 0; r < 4; ++r)
      m2[(m0 + lq * 4 + r) * MS + t * 16 + lrow] = silu_f(acc2[t][r] + bb);
  }
  __syncthreads();

  const int e2 = tid & 63, cg = tid >> 6, cb = cg * 32;
  const int r_e = rows[e2];
  const bool leader = (e2 == 0) || (rows[e2 - 1] != r_e);
  if (leader) {
    float sum[32];
#pragma unroll
    for (int j = 0; j < 32; ++j) sum[j] = m2[e2 * MS + cb + j];
    int f = e2 + 1;
    while (f < EPB && rows[f] == r_e) {
#pragma unroll
      for (int j = 0; j < 32; ++j) sum[j] += m2[f * MS + cb + j];
      ++f;
    }
    float* ap = agg + (size_t)r_e * HDIM + cb;
#pragma unroll
    for (int j = 0; j < 32; ++j) atomicAdd(&ap[j], sum[j]);
  }
}

// ==================== MFMA node update ====================
__global__ __launch_bounds__(256) void node_mfma_kernel(
    float* __restrict__ out_h, const float* __restrict__ agg,
    const ushort* __restrict__ enccs, const float* __restrict__ encb,
    const ushort* __restrict__ wqdcs, const float* __restrict__ decb,
    ushort* __restrict__ hbf) {
  __shared__ ushort A[EPB * NAS];
  __shared__ ushort wbuf[4096];
  __shared__ ushort m1[EPB * MS];
  const int tid = threadIdx.x;
  const int n0 = blockIdx.x * EPB;

  {
    const int e = tid >> 2, j = tid & 3;
    const int node = n0 + e;
    const float* src = (j < 2) ? (out_h + (size_t)node * HDIM + j * 64)
                               : (agg + (size_t)node * HDIM + (j - 2) * 64);
    const float sc = (j < 2) ? 1.0f : 0.01f;
    ushort* dst = (j < 2) ? (A + e * NAS + j * 64)
                          : (A + e * NAS + 128 + (j - 2) * 64);
    const float4* s4 = (const float4*)src;
#pragma unroll
    for (int i = 0; i < 16; ++i) {
      float4 v = s4[i];
      ushort4 o;
      o.x = f2bf(v.x * sc); o.y = f2bf(v.y * sc);
      o.z = f2bf(v.z * sc); o.w = f2bf(v.w * sc);
      ((ushort4*)dst)[i] = o;
    }
  }

  const int lane = tid & 63, wave = tid >> 6;
  const int m0 = wave * 16;
  const int lrow = lane & 15, lq = lane >> 4;

  f32x4 acc[8];
#pragma unroll
  for (int t = 0; t < 8; ++t) acc[t] = (f32x4){0.f, 0.f, 0.f, 0.f};
  for (int kt = 0; kt < 8; ++kt) {
    __syncthreads();
    {
      const uint4* src = (const uint4*)(enccs + kt * 4096);
      uint4* dw = (uint4*)wbuf;
      dw[tid] = src[tid];
      dw[tid + 256] = src[tid + 256];
    }
    __syncthreads();
    short8b af = *(const short8b*)(A + (m0 + lrow) * NAS + kt * 32 + lq * 8);
#pragma unroll
    for (int t = 0; t < 8; ++t) {
      short8b bfv = *(const short8b*)(wbuf + (t * 16 + lrow) * 32 + lq * 8);
      acc[t] = __builtin_amdgcn_mfma_f32_16x16x32_bf16(af, bfv, acc[t], 0, 0, 0);
    }
  }
#pragma unroll
  for (int t = 0; t < 8; ++t) {
    float bb = encb[t * 16 + lrow];
#pragma unroll
    for (int r = 0; r < 4; ++r) acc[t][r] += bb;
  }
  float ss[4] = {0.f, 0.f, 0.f, 0.f};
#pragma unroll
  for (int t = 0; t < 8; ++t)
#pragma unroll
    for (int r = 0; r < 4; ++r) ss[r] += acc[t][r] * acc[t][r];
#pragma unroll
  for (int m = 1; m < 16; m <<= 1) {
#pragma unroll
    for (int r = 0; r < 4; ++r) ss[r] += __shfl_xor(ss[r], m, 64);
  }
  float inv[4];
#pragma unroll
  for (int r = 0; r < 4; ++r) inv[r] = 1.0f / sqrtf(ss[r] + 1e-12f);
#pragma unroll
  for (int t = 0; t < 8; ++t)
#pragma unroll
    for (int r = 0; r < 4; ++r)
      m1[(m0 + lq * 4 + r) * MS + t * 16 + lrow] = f2bf(acc[t][r] * inv[r]);

  f32x4 acc2[8];
#pragma unroll
  for (int t = 0; t < 8; ++t) acc2[t] = (f32x4){0.f, 0.f, 0.f, 0.f};
  for (int kt = 0; kt < 4; ++kt) {
    __syncthreads();
    {
      const uint4* src = (const uint4*)(wqdcs + kt * 4096);
      uint4* dw = (uint4*)wbuf;
      dw[tid] = src[tid];
      dw[tid + 256] = src[tid + 256];
    }
    __syncthreads();
    short8b af = *(const short8b*)(m1 + (m0 + lrow) * MS + kt * 32 + lq * 8);
#pragma unroll
    for (int t = 0; t < 8; ++t) {
      short8b bfv = *(const short8b*)(wbuf + (t * 16 + lrow) * 32 + lq * 8);
      acc2[t] = __builtin_amdgcn_mfma_f32_16x16x32_bf16(af, bfv, acc2[t], 0, 0, 0);
    }
  }
#pragma unroll
  for (int t = 0; t < 8; ++t) {
    const int n = t * 16 + lrow;
    float bb = decb[n];
#pragma unroll
    for (int r = 0; r < 4; ++r) {
      const int node = n0 + m0 + lq * 4 + r;
      if (node < N_NODES) {
        size_t off = (size_t)node * HDIM + n;
        float hn = out_h[off] + acc2[t][r] + bb;
        out_h[off] = hn;
        hbf[off] = f2bf(hn);
      }
    }
  }
}

// ==================== MFMA coordinate head ====================
__global__ __launch_bounds__(256) void coord_mfma_kernel(
    const ushort* __restrict__ hbf, const int* __restrict__ ei,
    const float* __restrict__ x, const float* __restrict__ ea,
    const int* __restrict__ elist,
    const ushort* __restrict__ w1cs, const float* __restrict__ b1,
    const ushort* __restrict__ w2cs, const float* __restrict__ b2,
    const float* __restrict__ w3, float* __restrict__ xout) {
  __shared__ ushort A[EPB * AS];
  __shared__ ushort wbuf[4096];
  __shared__ ushort m1[EPB * MS];
  __shared__ int rows[EPB];
  __shared__ int colsA[EPB];
  __shared__ float tv[EPB];

  const int tid = threadIdx.x;
  const int i0 = blockIdx.x * EPB;

  {
    const int e = tid >> 2, j = tid & 3;
    const int edge = elist[i0 + e];
    const int r = ei[edge], c = ei[N_EDGES + edge];
    if (j == 0) { rows[e] = r; colsA[e] = c; }
    const uint4* hr = (const uint4*)(hbf + (size_t)r * HDIM + j * 32);
    const uint4* hc = (const uint4*)(hbf + (size_t)c * HDIM + j * 32);
    uint4* d1 = (uint4*)(A + e * AS + j * 32);
    uint4* d2 = (uint4*)(A + e * AS + 128 + j * 32);
    d1[0] = hr[0]; d1[1] = hr[1]; d1[2] = hr[2]; d1[3] = hr[3];
    d2[0] = hc[0]; d2[1] = hc[1]; d2[2] = hc[2]; d2[3] = hc[3];
    if (j == 3) {
      float dx = x[r * 3 + 0] - x[c * 3 + 0];
      float dy = x[r * 3 + 1] - x[c * 3 + 1];
      float dz = x[r * 3 + 2] - x[c * 3 + 2];
      ushort* dst = A + e * AS;
      dst[256] = f2bf(dx * dx + dy * dy + dz * dz);
      dst[257] = f2bf(ea[edge]);
#pragma unroll
      for (int z = 258; z < 288; ++z) dst[z] = 0;
    }
  }

  const int lane = tid & 63, wave = tid >> 6;
  const int m0 = wave * 16;
  const int lrow = lane & 15, lq = lane >> 4;

  f32x4 acc[8];
#pragma unroll
  for (int t = 0; t < 8; ++t) acc[t] = (f32x4){0.f, 0.f, 0.f, 0.f};
  for (int kt = 0; kt < 9; ++kt) {
    __syncthreads();
    {
      const uint4* src = (const uint4*)(w1cs + kt * 4096);
      uint4* dw = (uint4*)wbuf;
      dw[tid] = src[tid];
      dw[tid + 256] = src[tid + 256];
    }
    __syncthreads();
    short8b af = *(const short8b*)(A + (m0 + lrow) * AS + kt * 32 + lq * 8);
#pragma unroll
    for (int t = 0; t < 8; ++t) {
      short8b bfv = *(const short8b*)(wbuf + (t * 16 + lrow) * 32 + lq * 8);
      acc[t] = __builtin_amdgcn_mfma_f32_16x16x32_bf16(af, bfv, acc[t], 0, 0, 0);
    }
  }
#pragma unroll
  for (int t = 0; t < 8; ++t) {
    float bb = b1[t * 16 + lrow];
#pragma unroll
    for (int r = 0; r < 4; ++r)
      m1[(m0 + lq * 4 + r) * MS + t * 16 + lrow] = f2bf(silu_f(acc[t][r] + bb));
  }

  f32x4 acc2[8];
#pragma unroll
  for (int t = 0; t < 8; ++t) acc2[t] = (f32x4){0.f, 0.f, 0.f, 0.f};
  for (int kt = 0; kt < 4; ++kt) {
    __syncthreads();
    {
      const uint4* src = (const uint4*)(w2cs + kt * 4096);
      uint4* dw = (uint4*)wbuf;
      dw[tid] = src[tid];
      dw[tid + 256] = src[tid + 256];
    }
    __syncthreads();
    short8b af = *(const short8b*)(m1 + (m0 + lrow) * MS + kt * 32 + lq * 8);
#pragma unroll
    for (int t = 0; t < 8; ++t) {
      short8b bfv = *(const short8b*)(wbuf + (t * 16 + lrow) * 32 + lq * 8);
      acc2[t] = __builtin_amdgcn_mfma_f32_16x16x32_bf16(af, bfv, acc2[t], 0, 0, 0);
    }
  }
  float p[4] = {0.f, 0.f, 0.f, 0.f};
#pragma unroll
  for (int t = 0; t < 8; ++t) {
    const int n = t * 16 + lrow;
    float bb = b2[n];
    float wv = w3[n];
#pragma unroll
    for (int r = 0; r < 4; ++r) p[r] += silu_f(acc2[t][r] + bb) * wv;
  }
#pragma unroll
  for (int m = 1; m < 16; m <<= 1) {
#pragma unroll
    for (int r = 0; r < 4; ++r) p[r] += __shfl_xor(p[r], m, 64);
  }
  if (lrow == 0) {
#pragma unroll
    for (int r = 0; r < 4; ++r) tv[m0 + lq * 4 + r] = p[r] * 0.01f;
  }
  __syncthreads();
  if (tid < EPB) {
    const int e = tid;
    const int r_e = rows[e];
    const bool leader = (e == 0) || (rows[e - 1] != r_e);
    if (leader) {
      float sx = 0.f, sy = 0.f, sz = 0.f;
      int f = e;
      do {
        const int c = colsA[f];
        float dx = x[r_e * 3 + 0] - x[c * 3 + 0];
        float dy = x[r_e * 3 + 1] - x[c * 3 + 1];
        float dz = x[r_e * 3 + 2] - x[c * 3 + 2];
        float radial = dx * dx + dy * dy + dz * dz;
        float s = 1.0f / (sqrtf(radial + 1e-8f) + 1.0f);
        float t = tv[f];
        sx += dx * s * t; sy += dy * s * t; sz += dz * s * t;
        ++f;
      } while (f < EPB && rows[f] == r_e);
      atomicAdd(&xout[r_e * 3 + 0], sx);
      atomicAdd(&xout[r_e * 3 + 1], sy);
      atomicAdd(&xout[r_e * 3 + 2], sz);
    }
  }
}

extern "C" void kernel_launch(void* const* d_in, const int* in_sizes, int n_in,
                              void* d_out, int out_size, void* d_ws, size_t ws_size,
                              hipStream_t stream) {
  const float* h     = (const float*)d_in[0];
  const float* x     = (const float*)d_in[1];
  const int*   ei    = (const int*)d_in[2];
  const float* ea    = (const float*)d_in[3];
  const float* e_w1  = (const float*)d_in[4];
  const float* e_b1  = (const float*)d_in[5];
  const float* e_w2  = (const float*)d_in[6];
  const float* e_b2  = (const float*)d_in[7];
  const float* enc_w = (const float*)d_in[8];
  const float* enc_b = (const float*)d_in[9];
  const float* coeffs= (const float*)d_in[10];
  const float* A_re  = (const float*)d_in[11];
  const float* A_im  = (const float*)d_in[12];
  const float* dec_w = (const float*)d_in[13];
  const float* dec_b = (const float*)d_in[14];
  const float* c_w1  = (const float*)d_in[15];
  const float* c_b1  = (const float*)d_in[16];
  const float* c_w2  = (const float*)d_in[17];
  const float* c_b2  = (const float*)d_in[18];
  const float* c_w3  = (const float*)d_in[19];

  float* out = (float*)d_out;
  float* ws  = (float*)d_ws;

  float*  agg    = ws;                          // 3,840,000
  float2* binv   = (float2*)(ws + 3840000);     // 262,144 f (4 * 128*256 c)
  float2* qm     = (float2*)(ws + 4102144);     // 131,072 f
  float2* gkm    = (float2*)(ws + 4233216);     // 131,072 f
  float2* njm    = (float2*)(ws + 4364288);     // 131,072 f
  float2* um     = (float2*)(ws + 4495360);     //  65,536 f
  float*  wqd    = ws + 4560896;                //  32,768 f
  int*    perm   = (int*)(ws + 4593664);        //     128
  int*    cursor = (int*)(ws + 4593792);        //  30,000
  int*    elist  = (int*)(ws + 4623792);        // 480,000
  ushort* hbf    = (ushort*)(ws + 5103792);     // 1,920,000 f
  ushort* w1cs   = (ushort*)(ws + 7023792);
  ushort* w2cs   = (ushort*)(ws + 7060656);
  ushort* cw1cs  = (ushort*)(ws + 7077040);
  ushort* cw2cs  = (ushort*)(ws + 7095472);
  ushort* enccs  = (ushort*)(ws + 7103664);
  ushort* wqdcs  = (ushort*)(ws + 7136432);

  init_out_kernel<<<15000, 256, 0, stream>>>(h, x, out);

  // counting sort of edges by destination row
  hipMemsetAsync(cursor, 0, N_NODES * sizeof(int), stream);
  count_kernel<<<1875, 256, 0, stream>>>(ei, cursor);
  scan_kernel<<<1, 1024, 0, stream>>>(cursor);
  fill_kernel<<<1875, 256, 0, stream>>>(ei, cursor, elist);

  // quantum-operator precompute (tiny)
  perm_kernel<<<1, 128, 0, stream>>>(perm);
  gj_reg_kernel<<<4, 1024, 0, stream>>>(A_re, A_im, binv);
  qmat_kernel<<<dim3(64, 4), 256, 0, stream>>>(A_re, A_im, binv, qm);
  gk_kernel<<<dim3(64, 4), 256, 0, stream>>>(coeffs, gkm);
  nj_kernel<<<dim3(64, 4), 256, 0, stream>>>(qm, gkm, perm, njm);
  compose_kernel<<<dim3(64, 2), 256, 0, stream>>>(njm, um);
  wqd_kernel<<<dim3(64, 2), 256, 0, stream>>>(um, dec_w, wqd);

  // weight conversions to chunked bf16 [kt][n][kk]
  for (int l = 0; l < 2; ++l) {
    convert_w_kernel<<<144, 256, 0, stream>>>(e_w1 + (size_t)l * 258 * HDIM,
                                              w1cs + (size_t)l * 9 * 4096, 258, 9);
    convert_w_kernel<<<64, 256, 0, stream>>>(e_w2 + (size_t)l * HDIM * HDIM,
                                             w2cs + (size_t)l * 4 * 4096, 128, 4);
    convert_w_kernel<<<128, 256, 0, stream>>>(enc_w + (size_t)l * 256 * HDIM,
                                              enccs + (size_t)l * 8 * 4096, 256, 8);
    convert_w_kernel<<<64, 256, 0, stream>>>(wqd + (size_t)l * HDIM * HDIM,
                                             wqdcs + (size_t)l * 4 * 4096, 128, 4);
  }
  convert_w_kernel<<<144, 256, 0, stream>>>(c_w1, cw1cs, 258, 9);
  convert_w_kernel<<<64, 256, 0, stream>>>(c_w2, cw2cs, 128, 4);

  // initial bf16 h
  h_to_bf_kernel<<<3750, 256, 0, stream>>>(out, hbf);

  // two message-passing layers
  for (int l = 0; l < 2; ++l) {
    hipMemsetAsync(agg, 0, (size_t)N_NODES * HDIM * sizeof(float), stream);
    edge_mfma_kernel<<<N_EDGES / EPB, 256, 0, stream>>>(
        hbf, ei, x, ea, elist,
        w1cs + (size_t)l * 9 * 4096, e_b1 + l * HDIM,
        w2cs + (size_t)l * 4 * 4096, e_b2 + l * HDIM, agg);
    node_mfma_kernel<<<(N_NODES + EPB - 1) / EPB, 256, 0, stream>>>(
        out, agg,
        enccs + (size_t)l * 8 * 4096, enc_b + l * HDIM,
        wqdcs + (size_t)l * 4 * 4096, dec_b + l * HDIM, hbf);
  }

  // coordinate head
  coord_mfma_kernel<<<N_EDGES / EPB, 256, 0, stream>>>(
      hbf, ei, x, ea, elist, cw1cs, c_b1, cw2cs, c_b2, c_w3,
      out + (size_t)N_NODES * HDIM);
}

// Round 5
// 1725.607 us; speedup vs baseline: 6.8820x; 1.1014x over previous
//
#include <hip/hip_runtime.h>
#include <math.h>

#define N_NODES 30000
#define N_EDGES 480000
#define HDIM 128
#define EPB 64        // edges (or nodes) per MFMA block
#define AS 296        // A-tile row stride (bf16): stride%32 banks -> 2-way (free)
#define NAS 264       // node A-tile row stride (bf16)
#define MS 136        // m1 row stride (bf16) / m2 stride (f32)

typedef __attribute__((ext_vector_type(8))) short short8b;
typedef __attribute__((ext_vector_type(4))) float f32x4;

__device__ __forceinline__ float silu_f(float v) {
  return v / (1.0f + __expf(-v));
}

__device__ __forceinline__ unsigned short f2bf(float f) {
  unsigned int u = __float_as_uint(f);
  unsigned int r = u + 0x7fffu + ((u >> 16) & 1u);
  return (unsigned short)(r >> 16);
}

__device__ __forceinline__ float2 cmul(float2 a, float2 b) {
  return make_float2(a.x * b.x - a.y * b.y, a.x * b.y + a.y * b.x);
}

// ---------------- output init: out = [h | x] ----------------
__global__ void init_out_kernel(const float* __restrict__ h,
                                const float* __restrict__ x,
                                float* __restrict__ out) {
  int idx = blockIdx.x * 256 + threadIdx.x;
  out[idx] = h[idx];
  if (idx < N_NODES * 3) out[N_NODES * HDIM + idx] = x[idx];
}

// ---------------- h (fp32) -> hbf (bf16) ----------------
__global__ void h_to_bf_kernel(const float* __restrict__ h,
                               ushort* __restrict__ hbf) {
  int idx = blockIdx.x * 256 + threadIdx.x;
  float4 v = ((const float4*)h)[idx];
  ushort4 o;
  o.x = f2bf(v.x); o.y = f2bf(v.y); o.z = f2bf(v.z); o.w = f2bf(v.w);
  ((ushort4*)hbf)[idx] = o;
}

// ---------------- weight convert: W[K][128] fp32 -> [KT][128][32] bf16 ----
__global__ void convert_w_kernel(const float* __restrict__ W,
                                 ushort* __restrict__ dst, int Kreal, int KT) {
  int idx = blockIdx.x * 256 + threadIdx.x;
  if (idx >= KT * 4096) return;
  int kt = idx >> 12, rem = idx & 4095, n = rem >> 5, kk = rem & 31;
  int k = kt * 32 + kk;
  float v = (k < Kreal) ? W[(size_t)k * HDIM + n] : 0.0f;
  dst[idx] = f2bf(v);
}

// ---------------- counting sort of edges by destination row ----------------
__global__ void count_kernel(const int* __restrict__ ei, int* __restrict__ cursor) {
  int e = blockIdx.x * 256 + threadIdx.x;
  atomicAdd(&cursor[ei[e]], 1);
}

__global__ __launch_bounds__(1024) void scan_kernel(int* __restrict__ cursor) {
  __shared__ int sums[1024];
  const int tid = threadIdx.x;
  const int base = tid * 30;
  int local[30];
  int s = 0;
#pragma unroll
  for (int j = 0; j < 30; ++j) {
    int idx = base + j;
    int d = (idx < N_NODES) ? cursor[idx] : 0;
    local[j] = s;
    s += d;
  }
  sums[tid] = s;
  __syncthreads();
  for (int off = 1; off < 1024; off <<= 1) {
    int add = (tid >= off) ? sums[tid - off] : 0;
    __syncthreads();
    sums[tid] += add;
    __syncthreads();
  }
  int excl = (tid == 0) ? 0 : sums[tid - 1];
#pragma unroll
  for (int j = 0; j < 30; ++j) {
    int idx = base + j;
    if (idx < N_NODES) cursor[idx] = excl + local[j];
  }
}

__global__ void fill_kernel(const int* __restrict__ ei, int* __restrict__ cursor,
                            int* __restrict__ elist) {
  int e = blockIdx.x * 256 + threadIdx.x;
  int r = ei[e];
  int pos = atomicAdd(&cursor[r], 1);
  elist[pos] = e;
}

// ---------------- CNOT ring permutation ----------------
__global__ void perm_kernel(int* __restrict__ g) {
  int i = threadIdx.x;
  int v = i;
  const int cs[7] = {6, 5, 4, 3, 2, 1, 0};
  const int ts[7] = {0, 6, 5, 4, 3, 2, 1};
#pragma unroll
  for (int p = 0; p < 7; ++p) {
    int cb = (v >> (6 - cs[p])) & 1;
    v = v ^ (cb << (6 - ts[p]));
  }
  g[i] = v;
}

// ============ register-resident Gauss-Jordan (R3, verified) ========
__global__ __launch_bounds__(1024) void gj_reg_kernel(
    const float* __restrict__ Are, const float* __restrict__ Aim,
    float2* __restrict__ binv) {
  const int lj = blockIdx.x;
  const float* are = Are + (size_t)lj * 16384;
  const float* aim = Aim + (size_t)lj * 16384;
  float2* bout = binv + (size_t)lj * 32768;

  __shared__ float2 fbuf[128];
  __shared__ float2 rowbuf[256];
  __shared__ float2 sig[128];

  const int tid = threadIdx.x;
  const int c = tid & 255, rg = tid >> 8;
  const int r0 = rg * 32;

  float2 reg[32];
  if (c < 128) {
#pragma unroll
    for (int rr = 0; rr < 32; ++rr) {
      int r = r0 + rr;
      float re = are[r * 128 + c] + are[c * 128 + r];
      float im = aim[r * 128 + c] - aim[c * 128 + r];
      if (r == c) im += 1.0f;
      reg[rr] = make_float2(re, im);
    }
  } else {
    int cc = c - 128;
#pragma unroll
    for (int rr = 0; rr < 32; ++rr)
      reg[rr] = make_float2((r0 + rr == cc) ? 1.0f : 0.0f, 0.0f);
  }
  __syncthreads();

  for (int p = 0; p < 128; ++p) {
    if (c == p) {
#pragma unroll
      for (int rr = 0; rr < 32; ++rr) fbuf[r0 + rr] = reg[rr];
    }
    __syncthreads();
    float2 piv = fbuf[p];
    float d = piv.x * piv.x + piv.y * piv.y;
    float2 ip = make_float2(piv.x / d, -piv.y / d);
    if (tid == 0) sig[p] = ip;
    if (rg == (p >> 5)) {
      int pl = p & 31;
      float2 s = reg[0];
#pragma unroll
      for (int k = 1; k < 32; ++k)
        if (pl == k) s = reg[k];
      rowbuf[c] = s;
    }
    __syncthreads();
    if (c >= p && c <= p + 128) {
      float2 pr = cmul(ip, rowbuf[c]);
      int prr = p - r0;
#pragma unroll
      for (int rr = 0; rr < 32; ++rr) {
        if (rr != prr) {
          float2 f = fbuf[r0 + rr];
          reg[rr].x -= f.x * pr.x - f.y * pr.y;
          reg[rr].y -= f.x * pr.y + f.y * pr.x;
        }
      }
    }
    __syncthreads();
  }

  if (c >= 128) {
#pragma unroll
    for (int rr = 0; rr < 32; ++rr) {
      int r = r0 + rr;
      bout[r * 256 + c] = cmul(sig[r], reg[rr]);
    }
  }
}

// ---------------- q = (A_h - iI) * Binv ----------------
__global__ void qmat_kernel(const float* __restrict__ Are,
                            const float* __restrict__ Aim,
                            const float2* __restrict__ augg,
                            float2* __restrict__ qm) {
  int lj = blockIdx.y;
  int idx = blockIdx.x * 256 + threadIdx.x;
  int r = idx >> 7, c = idx & 127;
  const float* are = Are + (size_t)lj * 16384;
  const float* aim = Aim + (size_t)lj * 16384;
  const float2* binv = augg + (size_t)lj * 32768;
  float2 acc = make_float2(0.f, 0.f);
  for (int k = 0; k < 128; ++k) {
    float re = are[r * 128 + k] + are[k * 128 + r];
    float im = aim[r * 128 + k] - aim[k * 128 + r];
    if (k == r) im -= 1.0f;
    float2 b = binv[k * 256 + 128 + c];
    acc.x += re * b.x - im * b.y;
    acc.y += re * b.y + im * b.x;
  }
  qm[(size_t)lj * 16384 + idx] = acc;
}

// ---------------- Gk = (RY*RX)^(kron 7) ----------------
__global__ void gk_kernel(const float* __restrict__ coeffs,
                          float2* __restrict__ gkm) {
  int lj = blockIdx.y;
  float a = coeffs[lj * 2 + 0], b = coeffs[lj * 2 + 1];
  float ca = cosf(0.5f * a), sa = sinf(0.5f * a);
  float cb = cosf(0.5f * b), sb = sinf(0.5f * b);
  float2 G[2][2];
  G[0][0] = make_float2(cb * ca, sb * sa);
  G[0][1] = make_float2(-sb * ca, -cb * sa);
  G[1][0] = make_float2(sb * ca, -cb * sa);
  G[1][1] = make_float2(cb * ca, -sb * sa);
  int idx = blockIdx.x * 256 + threadIdx.x;
  int r = idx >> 7, c = idx & 127;
  float2 acc = make_float2(1.f, 0.f);
#pragma unroll
  for (int bit = 6; bit >= 0; --bit) {
    float2 g = G[(r >> bit) & 1][(c >> bit) & 1];
    acc = make_float2(acc.x * g.x - acc.y * g.y, acc.x * g.y + acc.y * g.x);
  }
  gkm[(size_t)lj * 16384 + idx] = acc;
}

// ---------------- N_j[i][c] = sum_k q[k][i] * Gk[g[c]][k] ----------------
__global__ void nj_kernel(const float2* __restrict__ qm,
                          const float2* __restrict__ gkm,
                          const int* __restrict__ g,
                          float2* __restrict__ njm) {
  int lj = blockIdx.y;
  int idx = blockIdx.x * 256 + threadIdx.x;
  int i = idx >> 7, c = idx & 127;
  int gc = g[c];
  const float2* q = qm + (size_t)lj * 16384;
  const float2* gk = gkm + (size_t)lj * 16384;
  float2 acc = make_float2(0.f, 0.f);
  for (int k = 0; k < 128; ++k) {
    float2 qa = q[k * 128 + i];
    float2 gb = gk[gc * 128 + k];
    acc.x += qa.x * gb.x - qa.y * gb.y;
    acc.y += qa.x * gb.y + qa.y * gb.x;
  }
  njm[(size_t)lj * 16384 + idx] = acc;
}

// ---------------- U_l = N_{l,0} @ N_{l,1} ----------------
__global__ void compose_kernel(const float2* __restrict__ njm,
                               float2* __restrict__ um) {
  int l = blockIdx.y;
  int idx = blockIdx.x * 256 + threadIdx.x;
  int i = idx >> 7, c = idx & 127;
  const float2* n0 = njm + (size_t)(l * 2 + 0) * 16384;
  const float2* n1 = njm + (size_t)(l * 2 + 1) * 16384;
  float2 acc = make_float2(0.f, 0.f);
  for (int k = 0; k < 128; ++k) {
    float2 a = n0[i * 128 + k];
    float2 b = n1[k * 128 + c];
    acc.x += a.x * b.x - a.y * b.y;
    acc.y += a.x * b.y + a.y * b.x;
  }
  um[(size_t)l * 16384 + idx] = acc;
}

// ---------------- Wqd_l = Re(U_l) @ dec_w_l ----------------
__global__ void wqd_kernel(const float2* __restrict__ um,
                           const float* __restrict__ decw,
                           float* __restrict__ wqd) {
  int l = blockIdx.y;
  int idx = blockIdx.x * 256 + threadIdx.x;
  int i = idx >> 7, c = idx & 127;
  const float2* u = um + (size_t)l * 16384;
  const float* dw = decw + (size_t)l * 16384;
  float acc = 0.f;
  for (int k = 0; k < 128; ++k) acc += u[i * 128 + k].x * dw[k * 128 + c];
  wqd[(size_t)l * 16384 + idx] = acc;
}

// ==================== MFMA edge MLP, register-resident weights =============
// 64 sorted edges/block. Wave w owns cols [w*32, w*32+32) (2 N-tiles) for
// ALL 4 M-tiles; its 26 B-fragments live in VGPRs (loaded once, no LDS
// staging, no per-kt barriers, no wbuf bank conflicts).
__global__ __launch_bounds__(256, 2) void edge_mfma_kernel(
    const ushort* __restrict__ hbf, const int* __restrict__ ei,
    const float* __restrict__ x, const float* __restrict__ ea,
    const int* __restrict__ elist,
    const ushort* __restrict__ w1cs, const float* __restrict__ b1,
    const ushort* __restrict__ w2cs, const float* __restrict__ b2,
    float* __restrict__ agg) {
  __shared__ ushort A[EPB * AS];      // 37,888 B ; m2 (f32, stride MS) overlays
  __shared__ ushort m1[EPB * MS];     // 17,408 B
  __shared__ int rows[EPB];
  float* m2 = (float*)A;

  const int tid = threadIdx.x;
  const int lane = tid & 63, wave = tid >> 6;
  const int lrow = lane & 15, lq = lane >> 4;
  const int wbase = wave * 32;

  // ---- B-fragments into registers ----
  short8b w1f[9][2], w2f[4][2];
#pragma unroll
  for (int kt = 0; kt < 9; ++kt)
#pragma unroll
    for (int nt = 0; nt < 2; ++nt)
      w1f[kt][nt] = *(const short8b*)(w1cs + kt * 4096 + (wbase + nt * 16 + lrow) * 32 + lq * 8);
#pragma unroll
  for (int kt = 0; kt < 4; ++kt)
#pragma unroll
    for (int nt = 0; nt < 2; ++nt)
      w2f[kt][nt] = *(const short8b*)(w2cs + kt * 4096 + (wbase + nt * 16 + lrow) * 32 + lq * 8);
  const float b1v[2] = {b1[wbase + lrow], b1[wbase + 16 + lrow]};
  const float b2v[2] = {b2[wbase + lrow], b2[wbase + 16 + lrow]};

  const int i0 = blockIdx.x * EPB;
  // ---- gather A ----
  {
    const int e = tid >> 2, j = tid & 3;
    const int edge = elist[i0 + e];
    const int r = ei[edge], c = ei[N_EDGES + edge];
    if (j == 0) rows[e] = r;
    const uint4* hr = (const uint4*)(hbf + (size_t)r * HDIM + j * 32);
    const uint4* hc = (const uint4*)(hbf + (size_t)c * HDIM + j * 32);
    uint4* d1 = (uint4*)(A + e * AS + j * 32);
    uint4* d2 = (uint4*)(A + e * AS + 128 + j * 32);
    d1[0] = hr[0]; d1[1] = hr[1]; d1[2] = hr[2]; d1[3] = hr[3];
    d2[0] = hc[0]; d2[1] = hc[1]; d2[2] = hc[2]; d2[3] = hc[3];
    if (j == 3) {
      float dx = x[r * 3 + 0] - x[c * 3 + 0];
      float dy = x[r * 3 + 1] - x[c * 3 + 1];
      float dz = x[r * 3 + 2] - x[c * 3 + 2];
      ushort* dst = A + e * AS;
      dst[256] = f2bf(dx * dx + dy * dy + dz * dz);
      dst[257] = f2bf(ea[edge]);
#pragma unroll
      for (int z = 258; z < 288; ++z) dst[z] = 0;
    }
  }
  __syncthreads();

  // ---- GEMM1: pure LDS+MFMA ----
  f32x4 acc[4][2];
#pragma unroll
  for (int mt = 0; mt < 4; ++mt)
#pragma unroll
    for (int nt = 0; nt < 2; ++nt) acc[mt][nt] = (f32x4){0.f, 0.f, 0.f, 0.f};
#pragma unroll
  for (int kt = 0; kt < 9; ++kt) {
    short8b af[4];
#pragma unroll
    for (int mt = 0; mt < 4; ++mt)
      af[mt] = *(const short8b*)(A + (mt * 16 + lrow) * AS + kt * 32 + lq * 8);
#pragma unroll
    for (int mt = 0; mt < 4; ++mt)
#pragma unroll
      for (int nt = 0; nt < 2; ++nt)
        acc[mt][nt] = __builtin_amdgcn_mfma_f32_16x16x32_bf16(af[mt], w1f[kt][nt], acc[mt][nt], 0, 0, 0);
  }
  // silu -> m1 (cols wbase..wbase+31, disjoint per wave)
#pragma unroll
  for (int mt = 0; mt < 4; ++mt)
#pragma unroll
    for (int nt = 0; nt < 2; ++nt)
#pragma unroll
      for (int r = 0; r < 4; ++r)
        m1[(mt * 16 + lq * 4 + r) * MS + wbase + nt * 16 + lrow] =
            f2bf(silu_f(acc[mt][nt][r] + b1v[nt]));
  __syncthreads();

  // ---- GEMM2 ----
  f32x4 acc2[4][2];
#pragma unroll
  for (int mt = 0; mt < 4; ++mt)
#pragma unroll
    for (int nt = 0; nt < 2; ++nt) acc2[mt][nt] = (f32x4){0.f, 0.f, 0.f, 0.f};
#pragma unroll
  for (int kt = 0; kt < 4; ++kt) {
    short8b af[4];
#pragma unroll
    for (int mt = 0; mt < 4; ++mt)
      af[mt] = *(const short8b*)(m1 + (mt * 16 + lrow) * MS + kt * 32 + lq * 8);
#pragma unroll
    for (int mt = 0; mt < 4; ++mt)
#pragma unroll
      for (int nt = 0; nt < 2; ++nt)
        acc2[mt][nt] = __builtin_amdgcn_mfma_f32_16x16x32_bf16(af[mt], w2f[kt][nt], acc2[mt][nt], 0, 0, 0);
  }
  // m2 overlays A (all A reads completed before the m1-ready barrier)
#pragma unroll
  for (int mt = 0; mt < 4; ++mt)
#pragma unroll
    for (int nt = 0; nt < 2; ++nt)
#pragma unroll
      for (int r = 0; r < 4; ++r)
        m2[(mt * 16 + lq * 4 + r) * MS + wbase + nt * 16 + lrow] =
            silu_f(acc2[mt][nt][r] + b2v[nt]);
  __syncthreads();

  // ---- segmented reduce over sorted rows + atomics ----
  const int e2 = tid & 63, cg = tid >> 6, cb = cg * 32;
  const int r_e = rows[e2];
  const bool leader = (e2 == 0) || (rows[e2 - 1] != r_e);
  if (leader) {
    float sum[32];
#pragma unroll
    for (int j = 0; j < 32; ++j) sum[j] = m2[e2 * MS + cb + j];
    int f = e2 + 1;
    while (f < EPB && rows[f] == r_e) {
#pragma unroll
      for (int j = 0; j < 32; ++j) sum[j] += m2[f * MS + cb + j];
      ++f;
    }
    float* ap = agg + (size_t)r_e * HDIM + cb;
#pragma unroll
    for (int j = 0; j < 32; ++j) atomicAdd(&ap[j], sum[j]);
  }
}

// ==================== MFMA node update, register-resident weights ==========
__global__ __launch_bounds__(256, 2) void node_mfma_kernel(
    float* __restrict__ out_h, const float* __restrict__ agg,
    const ushort* __restrict__ enccs, const float* __restrict__ encb,
    const ushort* __restrict__ wqdcs, const float* __restrict__ decb,
    ushort* __restrict__ hbf) {
  __shared__ ushort A[EPB * NAS];     // 33,792 B
  __shared__ ushort m1[EPB * MS];     // 17,408 B
  __shared__ float nbuf[4 * EPB];     // per-wave rownorm partials
  const int tid = threadIdx.x;
  const int n0 = blockIdx.x * EPB;

  const int lane = tid & 63, wave = tid >> 6;
  const int lrow = lane & 15, lq = lane >> 4;
  const int wbase = wave * 32;

  short8b wef[8][2], wqf[4][2];
#pragma unroll
  for (int kt = 0; kt < 8; ++kt)
#pragma unroll
    for (int nt = 0; nt < 2; ++nt)
      wef[kt][nt] = *(const short8b*)(enccs + kt * 4096 + (wbase + nt * 16 + lrow) * 32 + lq * 8);
#pragma unroll
  for (int kt = 0; kt < 4; ++kt)
#pragma unroll
    for (int nt = 0; nt < 2; ++nt)
      wqf[kt][nt] = *(const short8b*)(wqdcs + kt * 4096 + (wbase + nt * 16 + lrow) * 32 + lq * 8);
  const float ebv[2] = {encb[wbase + lrow], encb[wbase + 16 + lrow]};
  const float dbv[2] = {decb[wbase + lrow], decb[wbase + 16 + lrow]};

  // ---- build A = [h | agg*0.01] in bf16 ----
  {
    const int e = tid >> 2, j = tid & 3;
    int node = n0 + e;
    if (node >= N_NODES) node = N_NODES - 1;   // clamp (rows not written back)
    const float* src = (j < 2) ? (out_h + (size_t)node * HDIM + j * 64)
                               : (agg + (size_t)node * HDIM + (j - 2) * 64);
    const float sc = (j < 2) ? 1.0f : 0.01f;
    ushort* dst = (j < 2) ? (A + e * NAS + j * 64)
                          : (A + e * NAS + 128 + (j - 2) * 64);
    const float4* s4 = (const float4*)src;
#pragma unroll
    for (int i = 0; i < 16; ++i) {
      float4 v = s4[i];
      ushort4 o;
      o.x = f2bf(v.x * sc); o.y = f2bf(v.y * sc);
      o.z = f2bf(v.z * sc); o.w = f2bf(v.w * sc);
      ((ushort4*)dst)[i] = o;
    }
  }
  __syncthreads();

  // ---- GEMM1: q = A @ enc ----
  f32x4 acc[4][2];
#pragma unroll
  for (int mt = 0; mt < 4; ++mt)
#pragma unroll
    for (int nt = 0; nt < 2; ++nt) acc[mt][nt] = (f32x4){0.f, 0.f, 0.f, 0.f};
#pragma unroll
  for (int kt = 0; kt < 8; ++kt) {
    short8b af[4];
#pragma unroll
    for (int mt = 0; mt < 4; ++mt)
      af[mt] = *(const short8b*)(A + (mt * 16 + lrow) * NAS + kt * 32 + lq * 8);
#pragma unroll
    for (int mt = 0; mt < 4; ++mt)
#pragma unroll
      for (int nt = 0; nt < 2; ++nt)
        acc[mt][nt] = __builtin_amdgcn_mfma_f32_16x16x32_bf16(af[mt], wef[kt][nt], acc[mt][nt], 0, 0, 0);
  }
  // bias + per-row sum-of-squares (wave partial over its 32 cols)
#pragma unroll
  for (int mt = 0; mt < 4; ++mt) {
    float ssp[4] = {0.f, 0.f, 0.f, 0.f};
#pragma unroll
    for (int nt = 0; nt < 2; ++nt)
#pragma unroll
      for (int r = 0; r < 4; ++r) {
        acc[mt][nt][r] += ebv[nt];
        ssp[r] += acc[mt][nt][r] * acc[mt][nt][r];
      }
#pragma unroll
    for (int m = 1; m < 16; m <<= 1)
#pragma unroll
      for (int r = 0; r < 4; ++r) ssp[r] += __shfl_xor(ssp[r], m, 64);
    if (lrow == 0) {
#pragma unroll
      for (int r = 0; r < 4; ++r)
        nbuf[wave * EPB + mt * 16 + lq * 4 + r] = ssp[r];
    }
  }
  __syncthreads();
  // normalize -> m1 (bf16)
#pragma unroll
  for (int mt = 0; mt < 4; ++mt)
#pragma unroll
    for (int r = 0; r < 4; ++r) {
      const int row = mt * 16 + lq * 4 + r;
      float sum = nbuf[row] + nbuf[EPB + row] + nbuf[2 * EPB + row] + nbuf[3 * EPB + row];
      float inv = 1.0f / sqrtf(sum + 1e-12f);
#pragma unroll
      for (int nt = 0; nt < 2; ++nt)
        m1[row * MS + wbase + nt * 16 + lrow] = f2bf(acc[mt][nt][r] * inv);
    }
  __syncthreads();

  // ---- GEMM2: dec = m1 @ Wqd ----
  f32x4 acc2[4][2];
#pragma unroll
  for (int mt = 0; mt < 4; ++mt)
#pragma unroll
    for (int nt = 0; nt < 2; ++nt) acc2[mt][nt] = (f32x4){0.f, 0.f, 0.f, 0.f};
#pragma unroll
  for (int kt = 0; kt < 4; ++kt) {
    short8b af[4];
#pragma unroll
    for (int mt = 0; mt < 4; ++mt)
      af[mt] = *(const short8b*)(m1 + (mt * 16 + lrow) * MS + kt * 32 + lq * 8);
#pragma unroll
    for (int mt = 0; mt < 4; ++mt)
#pragma unroll
      for (int nt = 0; nt < 2; ++nt)
        acc2[mt][nt] = __builtin_amdgcn_mfma_f32_16x16x32_bf16(af[mt], wqf[kt][nt], acc2[mt][nt], 0, 0, 0);
  }
  // epilogue: h_new = h_old + dec + dec_b
#pragma unroll
  for (int mt = 0; mt < 4; ++mt)
#pragma unroll
    for (int nt = 0; nt < 2; ++nt) {
      const int n = wbase + nt * 16 + lrow;
#pragma unroll
      for (int r = 0; r < 4; ++r) {
        const int node = n0 + mt * 16 + lq * 4 + r;
        if (node < N_NODES) {
          size_t off = (size_t)node * HDIM + n;
          float hn = out_h[off] + acc2[mt][nt][r] + dbv[nt];
          out_h[off] = hn;
          hbf[off] = f2bf(hn);
        }
      }
    }
}

// ==================== MFMA coordinate head, register-resident weights ======
__global__ __launch_bounds__(256, 2) void coord_mfma_kernel(
    const ushort* __restrict__ hbf, const int* __restrict__ ei,
    const float* __restrict__ x, const float* __restrict__ ea,
    const int* __restrict__ elist,
    const ushort* __restrict__ w1cs, const float* __restrict__ b1,
    const ushort* __restrict__ w2cs, const float* __restrict__ b2,
    const float* __restrict__ w3, float* __restrict__ xout) {
  __shared__ ushort A[EPB * AS];
  __shared__ ushort m1[EPB * MS];
  __shared__ int rows[EPB];
  __shared__ int colsA[EPB];
  __shared__ float pbuf[4 * EPB];
  __shared__ float tv[EPB];

  const int tid = threadIdx.x;
  const int lane = tid & 63, wave = tid >> 6;
  const int lrow = lane & 15, lq = lane >> 4;
  const int wbase = wave * 32;

  short8b w1f[9][2], w2f[4][2];
#pragma unroll
  for (int kt = 0; kt < 9; ++kt)
#pragma unroll
    for (int nt = 0; nt < 2; ++nt)
      w1f[kt][nt] = *(const short8b*)(w1cs + kt * 4096 + (wbase + nt * 16 + lrow) * 32 + lq * 8);
#pragma unroll
  for (int kt = 0; kt < 4; ++kt)
#pragma unroll
    for (int nt = 0; nt < 2; ++nt)
      w2f[kt][nt] = *(const short8b*)(w2cs + kt * 4096 + (wbase + nt * 16 + lrow) * 32 + lq * 8);
  const float b1v[2] = {b1[wbase + lrow], b1[wbase + 16 + lrow]};
  const float b2v[2] = {b2[wbase + lrow], b2[wbase + 16 + lrow]};
  const float w3v[2] = {w3[wbase + lrow], w3[wbase + 16 + lrow]};

  const int i0 = blockIdx.x * EPB;
  {
    const int e = tid >> 2, j = tid & 3;
    const int edge = elist[i0 + e];
    const int r = ei[edge], c = ei[N_EDGES + edge];
    if (j == 0) { rows[e] = r; colsA[e] = c; }
    const uint4* hr = (const uint4*)(hbf + (size_t)r * HDIM + j * 32);
    const uint4* hc = (const uint4*)(hbf + (size_t)c * HDIM + j * 32);
    uint4* d1 = (uint4*)(A + e * AS + j * 32);
    uint4* d2 = (uint4*)(A + e * AS + 128 + j * 32);
    d1[0] = hr[0]; d1[1] = hr[1]; d1[2] = hr[2]; d1[3] = hr[3];
    d2[0] = hc[0]; d2[1] = hc[1]; d2[2] = hc[2]; d2[3] = hc[3];
    if (j == 3) {
      float dx = x[r * 3 + 0] - x[c * 3 + 0];
      float dy = x[r * 3 + 1] - x[c * 3 + 1];
      float dz = x[r * 3 + 2] - x[c * 3 + 2];
      ushort* dst = A + e * AS;
      dst[256] = f2bf(dx * dx + dy * dy + dz * dz);
      dst[257] = f2bf(ea[edge]);
#pragma unroll
      for (int z = 258; z < 288; ++z) dst[z] = 0;
    }
  }
  __syncthreads();

  f32x4 acc[4][2];
#pragma unroll
  for (int mt = 0; mt < 4; ++mt)
#pragma unroll
    for (int nt = 0; nt < 2; ++nt) acc[mt][nt] = (f32x4){0.f, 0.f, 0.f, 0.f};
#pragma unroll
  for (int kt = 0; kt < 9; ++kt) {
    short8b af[4];
#pragma unroll
    for (int mt = 0; mt < 4; ++mt)
      af[mt] = *(const short8b*)(A + (mt * 16 + lrow) * AS + kt * 32 + lq * 8);
#pragma unroll
    for (int mt = 0; mt < 4; ++mt)
#pragma unroll
      for (int nt = 0; nt < 2; ++nt)
        acc[mt][nt] = __builtin_amdgcn_mfma_f32_16x16x32_bf16(af[mt], w1f[kt][nt], acc[mt][nt], 0, 0, 0);
  }
#pragma unroll
  for (int mt = 0; mt < 4; ++mt)
#pragma unroll
    for (int nt = 0; nt < 2; ++nt)
#pragma unroll
      for (int r = 0; r < 4; ++r)
        m1[(mt * 16 + lq * 4 + r) * MS + wbase + nt * 16 + lrow] =
            f2bf(silu_f(acc[mt][nt][r] + b1v[nt]));
  __syncthreads();

  f32x4 acc2[4][2];
#pragma unroll
  for (int mt = 0; mt < 4; ++mt)
#pragma unroll
    for (int nt = 0; nt < 2; ++nt) acc2[mt][nt] = (f32x4){0.f, 0.f, 0.f, 0.f};
#pragma unroll
  for (int kt = 0; kt < 4; ++kt) {
    short8b af[4];
#pragma unroll
    for (int mt = 0; mt < 4; ++mt)
      af[mt] = *(const short8b*)(m1 + (mt * 16 + lrow) * MS + kt * 32 + lq * 8);
#pragma unroll
    for (int mt = 0; mt < 4; ++mt)
#pragma unroll
      for (int nt = 0; nt < 2; ++nt)
        acc2[mt][nt] = __builtin_amdgcn_mfma_f32_16x16x32_bf16(af[mt], w2f[kt][nt], acc2[mt][nt], 0, 0, 0);
  }
  // per-row partial of sum_n silu(.)*w3 over this wave's 32 cols
#pragma unroll
  for (int mt = 0; mt < 4; ++mt) {
    float p[4] = {0.f, 0.f, 0.f, 0.f};
#pragma unroll
    for (int nt = 0; nt < 2; ++nt)
#pragma unroll
      for (int r = 0; r < 4; ++r)
        p[r] += silu_f(acc2[mt][nt][r] + b2v[nt]) * w3v[nt];
#pragma unroll
    for (int m = 1; m < 16; m <<= 1)
#pragma unroll
      for (int r = 0; r < 4; ++r) p[r] += __shfl_xor(p[r], m, 64);
    if (lrow == 0) {
#pragma unroll
      for (int r = 0; r < 4; ++r)
        pbuf[wave * EPB + mt * 16 + lq * 4 + r] = p[r];
    }
  }
  __syncthreads();
  if (tid < EPB) {
    tv[tid] = (pbuf[tid] + pbuf[EPB + tid] + pbuf[2 * EPB + tid] + pbuf[3 * EPB + tid]) * 0.01f;
  }
  __syncthreads();
  if (tid < EPB) {
    const int e = tid;
    const int r_e = rows[e];
    const bool leader = (e == 0) || (rows[e - 1] != r_e);
    if (leader) {
      float sx = 0.f, sy = 0.f, sz = 0.f;
      int f = e;
      do {
        const int c = colsA[f];
        float dx = x[r_e * 3 + 0] - x[c * 3 + 0];
        float dy = x[r_e * 3 + 1] - x[c * 3 + 1];
        float dz = x[r_e * 3 + 2] - x[c * 3 + 2];
        float radial = dx * dx + dy * dy + dz * dz;
        float s = 1.0f / (sqrtf(radial + 1e-8f) + 1.0f);
        float t = tv[f];
        sx += dx * s * t; sy += dy * s * t; sz += dz * s * t;
        ++f;
      } while (f < EPB && rows[f] == r_e);
      atomicAdd(&xout[r_e * 3 + 0], sx);
      atomicAdd(&xout[r_e * 3 + 1], sy);
      atomicAdd(&xout[r_e * 3 + 2], sz);
    }
  }
}

extern "C" void kernel_launch(void* const* d_in, const int* in_sizes, int n_in,
                              void* d_out, int out_size, void* d_ws, size_t ws_size,
                              hipStream_t stream) {
  const float* h     = (const float*)d_in[0];
  const float* x     = (const float*)d_in[1];
  const int*   ei    = (const int*)d_in[2];
  const float* ea    = (const float*)d_in[3];
  const float* e_w1  = (const float*)d_in[4];
  const float* e_b1  = (const float*)d_in[5];
  const float* e_w2  = (const float*)d_in[6];
  const float* e_b2  = (const float*)d_in[7];
  const float* enc_w = (const float*)d_in[8];
  const float* enc_b = (const float*)d_in[9];
  const float* coeffs= (const float*)d_in[10];
  const float* A_re  = (const float*)d_in[11];
  const float* A_im  = (const float*)d_in[12];
  const float* dec_w = (const float*)d_in[13];
  const float* dec_b = (const float*)d_in[14];
  const float* c_w1  = (const float*)d_in[15];
  const float* c_b1  = (const float*)d_in[16];
  const float* c_w2  = (const float*)d_in[17];
  const float* c_b2  = (const float*)d_in[18];
  const float* c_w3  = (const float*)d_in[19];

  float* out = (float*)d_out;
  float* ws  = (float*)d_ws;

  float*  agg    = ws;                          // 3,840,000
  float2* binv   = (float2*)(ws + 3840000);     // 262,144 f
  float2* qm     = (float2*)(ws + 4102144);     // 131,072 f
  float2* gkm    = (float2*)(ws + 4233216);     // 131,072 f
  float2* njm    = (float2*)(ws + 4364288);     // 131,072 f
  float2* um     = (float2*)(ws + 4495360);     //  65,536 f
  float*  wqd    = ws + 4560896;                //  32,768 f
  int*    perm   = (int*)(ws + 4593664);        //     128
  int*    cursor = (int*)(ws + 4593792);        //  30,000
  int*    elist  = (int*)(ws + 4623792);        // 480,000
  ushort* hbf    = (ushort*)(ws + 5103792);     // 1,920,000 f
  ushort* w1cs   = (ushort*)(ws + 7023792);
  ushort* w2cs   = (ushort*)(ws + 7060656);
  ushort* cw1cs  = (ushort*)(ws + 7077040);
  ushort* cw2cs  = (ushort*)(ws + 7095472);
  ushort* enccs  = (ushort*)(ws + 7103664);
  ushort* wqdcs  = (ushort*)(ws + 7136432);

  init_out_kernel<<<15000, 256, 0, stream>>>(h, x, out);

  // counting sort of edges by destination row
  hipMemsetAsync(cursor, 0, N_NODES * sizeof(int), stream);
  count_kernel<<<1875, 256, 0, stream>>>(ei, cursor);
  scan_kernel<<<1, 1024, 0, stream>>>(cursor);
  fill_kernel<<<1875, 256, 0, stream>>>(ei, cursor, elist);

  // quantum-operator precompute (tiny)
  perm_kernel<<<1, 128, 0, stream>>>(perm);
  gj_reg_kernel<<<4, 1024, 0, stream>>>(A_re, A_im, binv);
  qmat_kernel<<<dim3(64, 4), 256, 0, stream>>>(A_re, A_im, binv, qm);
  gk_kernel<<<dim3(64, 4), 256, 0, stream>>>(coeffs, gkm);
  nj_kernel<<<dim3(64, 4), 256, 0, stream>>>(qm, gkm, perm, njm);
  compose_kernel<<<dim3(64, 2), 256, 0, stream>>>(njm, um);
  wqd_kernel<<<dim3(64, 2), 256, 0, stream>>>(um, dec_w, wqd);

  // weight conversions to chunked bf16 [kt][n][kk]
  for (int l = 0; l < 2; ++l) {
    convert_w_kernel<<<144, 256, 0, stream>>>(e_w1 + (size_t)l * 258 * HDIM,
                                              w1cs + (size_t)l * 9 * 4096, 258, 9);
    convert_w_kernel<<<64, 256, 0, stream>>>(e_w2 + (size_t)l * HDIM * HDIM,
                                             w2cs + (size_t)l * 4 * 4096, 128, 4);
    convert_w_kernel<<<128, 256, 0, stream>>>(enc_w + (size_t)l * 256 * HDIM,
                                              enccs + (size_t)l * 8 * 4096, 256, 8);
    convert_w_kernel<<<64, 256, 0, stream>>>(wqd + (size_t)l * HDIM * HDIM,
                                             wqdcs + (size_t)l * 4 * 4096, 128, 4);
  }
  convert_w_kernel<<<144, 256, 0, stream>>>(c_w1, cw1cs, 258, 9);
  convert_w_kernel<<<64, 256, 0, stream>>>(c_w2, cw2cs, 128, 4);

  // initial bf16 h
  h_to_bf_kernel<<<3750, 256, 0, stream>>>(out, hbf);

  // two message-passing layers
  for (int l = 0; l < 2; ++l) {
    hipMemsetAsync(agg, 0, (size_t)N_NODES * HDIM * sizeof(float), stream);
    edge_mfma_kernel<<<N_EDGES / EPB, 256, 0, stream>>>(
        hbf, ei, x, ea, elist,
        w1cs + (size_t)l * 9 * 4096, e_b1 + l * HDIM,
        w2cs + (size_t)l * 4 * 4096, e_b2 + l * HDIM, agg);
    node_mfma_kernel<<<(N_NODES + EPB - 1) / EPB, 256, 0, stream>>>(
        out, agg,
        enccs + (size_t)l * 8 * 4096, enc_b + l * HDIM,
        wqdcs + (size_t)l * 4 * 4096, dec_b + l * HDIM, hbf);
  }

  // coordinate head
  coord_mfma_kernel<<<N_EDGES / EPB, 256, 0, stream>>>(
      hbf, ei, x, ea, elist, cw1cs, c_b1, cw2cs, c_b2, c_w3,
      out + (size_t)N_NODES * HDIM);
}